// Round 16
// baseline (414.216 us; speedup 1.0000x reference)
//
#include <hip/hip_runtime.h>
#include <hip/hip_bf16.h>

#define MM 131072

typedef __attribute__((ext_vector_type(8))) short short8;
typedef __attribute__((ext_vector_type(4))) float f32x4;

#define GLP(p) (const __attribute__((address_space(1))) void*)(p)
#define LDSP(p) (__attribute__((address_space(3))) void*)(p)

static __device__ __forceinline__ unsigned short f2bf(float f) {
    union { float f; unsigned int u; } v; v.f = f;
    unsigned int r = v.u + 0x7FFF + ((v.u >> 16) & 1);  // RNE
    return (unsigned short)(r >> 16);
}
static __device__ __forceinline__ float bf2f(unsigned short h) {
    union { float f; unsigned int u; } v; v.u = ((unsigned int)h) << 16;
    return v.f;
}

// ===========================================================================
// Launch A: prep (conv x/u -> bf16, x->y cols 0..63, 6x W->WT) + wgemm L1
// ===========================================================================
__global__ __launch_bounds__(256) void prepA(
    const float* __restrict__ x, const float* __restrict__ u,
    __hip_bfloat16* __restrict__ xb, __hip_bfloat16* __restrict__ ub,
    float* __restrict__ y,
    const float* __restrict__ W0, const float* __restrict__ W1,
    const float* __restrict__ W2, const float* __restrict__ W3,
    const float* __restrict__ W4, const float* __restrict__ W5,
    __hip_bfloat16* __restrict__ T0, __hip_bfloat16* __restrict__ T1,
    __hip_bfloat16* __restrict__ T2, __hip_bfloat16* __restrict__ T3,
    __hip_bfloat16* __restrict__ T4, __hip_bfloat16* __restrict__ T5,
    const float* __restrict__ WK, const float* __restrict__ WB,
    float* __restrict__ W2f, float* __restrict__ WBWf)
{
    __shared__ __align__(16) float As[16][68];
    __shared__ __align__(16) float Ws[16][64];

    if (blockIdx.x < 16384) {
        int i = blockIdx.x * 256 + threadIdx.x;
        const float* s; __hip_bfloat16* d; int j; bool isx;
        if (i < 2097152) { s = x; d = xb; j = i; isx = true; }
        else             { s = u; d = ub; j = i - 2097152; isx = false; }
        const float4 v = ((const float4*)s)[j];
        union { unsigned short h[4]; uint2 u2; } p;
        p.h[0] = f2bf(v.x); p.h[1] = f2bf(v.y);
        p.h[2] = f2bf(v.z); p.h[3] = f2bf(v.w);
        ((uint2*)d)[j] = p.u2;
        if (isx) {
            const int r = j >> 4, q = j & 15;
            ((float4*)(y + (size_t)r * 256))[q] = v;
        }
    } else if (blockIdx.x < 17408) {
        const int b = blockIdx.x - 16384;
        const float* W; __hip_bfloat16* T; int K, N, i0;
        if      (b < 64)  { W = W0; T = T0; K = 64;  N = 256; i0 = b; }
        else if (b < 320) { W = W1; T = T1; K = 256; N = 256; i0 = b - 64; }
        else if (b < 512) { W = W2; T = T2; K = 256; N = 192; i0 = b - 320; }
        else if (b < 576) { W = W3; T = T3; K = 64;  N = 256; i0 = b - 512; }
        else if (b < 768) { W = W4; T = T4; K = 256; N = 192; i0 = b - 576; }
        else              { W = W5; T = T5; K = 256; N = 256; i0 = b - 768; }
        const int i = i0 * 256 + threadIdx.x;
        if (i < K * N) {
            const int n = i / K, k = i - n * K;
            T[i] = __float2bfloat16(W[(size_t)k * N + n]);
        }
    } else {
        const int tile = blockIdx.x - 17408;
        const int e  = tile >> 4;
        const int tl = tile & 15;
        const float* A = e ? WB : WK;
        const float* W = WK;
        float*       C = e ? WBWf : W2f;
        const int row0 = (tl >> 2) * 64;
        const int col0 = (tl & 3) * 64;
        const int tx = threadIdx.x & 15;
        const int ty = threadIdx.x >> 4;
        float acc[4][4] = {};
        for (int k0 = 0; k0 < 256; k0 += 16) {
            {
                const int kk = threadIdx.x & 15;
                const int r  = threadIdx.x >> 4;
                #pragma unroll
                for (int rr = 0; rr < 4; ++rr)
                    As[kk][r + rr * 16] = A[(size_t)(row0 + r + rr * 16) * 256 + k0 + kk];
            }
            {
                const int n  = threadIdx.x & 63;
                const int kz = threadIdx.x >> 6;
                #pragma unroll
                for (int kq = 0; kq < 4; ++kq) {
                    const int kk = kz + kq * 4;
                    Ws[kk][n] = W[(size_t)(k0 + kk) * 256 + col0 + n];
                }
            }
            __syncthreads();
            #pragma unroll
            for (int kk = 0; kk < 16; ++kk) {
                const float4 a4 = *(const float4*)&As[kk][ty * 4];
                const float4 w4 = *(const float4*)&Ws[kk][tx * 4];
                const float av[4] = {a4.x, a4.y, a4.z, a4.w};
                const float wv[4] = {w4.x, w4.y, w4.z, w4.w};
                #pragma unroll
                for (int i = 0; i < 4; ++i)
                    #pragma unroll
                    for (int j = 0; j < 4; ++j)
                        acc[i][j] += av[i] * wv[j];
            }
            __syncthreads();
        }
        #pragma unroll
        for (int i = 0; i < 4; ++i)
            #pragma unroll
            for (int j = 0; j < 4; ++j)
                C[(size_t)(row0 + ty * 4 + i) * 256 + col0 + tx * 4 + j] = acc[i][j];
    }
}

// ===========================================================================
// Launch B: wgemm L2 (4 GEMMs: W3, W4, WBW2, WBW3)
// ===========================================================================
struct G5 { const float* a[5]; const float* b[5]; float* c[5]; };

__global__ __launch_bounds__(256) void wgemm(G5 P)
{
    __shared__ __align__(16) float As[16][68];
    __shared__ __align__(16) float Ws[16][64];

    const int e  = blockIdx.x >> 4;
    const int tl = blockIdx.x & 15;
    const float* A = P.a[e];
    const float* W = P.b[e];
    float*       C = P.c[e];
    const int row0 = (tl >> 2) * 64;
    const int col0 = (tl & 3) * 64;

    const int tx = threadIdx.x & 15;
    const int ty = threadIdx.x >> 4;

    float acc[4][4] = {};

    for (int k0 = 0; k0 < 256; k0 += 16) {
        {
            const int kk = threadIdx.x & 15;
            const int r  = threadIdx.x >> 4;
            #pragma unroll
            for (int rr = 0; rr < 4; ++rr)
                As[kk][r + rr * 16] = A[(size_t)(row0 + r + rr * 16) * 256 + k0 + kk];
        }
        {
            const int n  = threadIdx.x & 63;
            const int kz = threadIdx.x >> 6;
            #pragma unroll
            for (int kq = 0; kq < 4; ++kq) {
                const int kk = kz + kq * 4;
                Ws[kk][n] = W[(size_t)(k0 + kk) * 256 + col0 + n];
            }
        }
        __syncthreads();
        #pragma unroll
        for (int kk = 0; kk < 16; ++kk) {
            const float4 a4 = *(const float4*)&As[kk][ty * 4];
            const float4 w4 = *(const float4*)&Ws[kk][tx * 4];
            const float av[4] = {a4.x, a4.y, a4.z, a4.w};
            const float wv[4] = {w4.x, w4.y, w4.z, w4.w};
            #pragma unroll
            for (int i = 0; i < 4; ++i)
                #pragma unroll
                for (int j = 0; j < 4; ++j)
                    acc[i][j] += av[i] * wv[j];
        }
        __syncthreads();
    }

    #pragma unroll
    for (int i = 0; i < 4; ++i)
        #pragma unroll
        for (int j = 0; j < 4; ++j)
            C[(size_t)(row0 + ty * 4 + i) * 256 + col0 + tx * 4 + j] = acc[i][j];
}

// ===========================================================================
// ffx body (3-stage x-path), rows = row0 + r*rs (rs=1 normal; rs=256 for the
// t=0-only side job). smem carve: I 64KB | Bs 64KB | As 16KB.
// ===========================================================================
static __device__ void ffx_impl(
    const __hip_bfloat16* __restrict__ x_bf,
    const __hip_bfloat16* __restrict__ W1T, const float* __restrict__ b1,
    const __hip_bfloat16* __restrict__ W2T, const float* __restrict__ b2,
    const __hip_bfloat16* __restrict__ W3T,
    float* __restrict__ y, int row0, int rs, char* smem, int tid)
{
    __hip_bfloat16* I  = (__hip_bfloat16*)smem;
    __hip_bfloat16* Bs = (__hip_bfloat16*)(smem + 65536);
    __hip_bfloat16* As = (__hip_bfloat16*)(smem + 131072);

    const int lane = tid & 63;
    const int wid  = tid >> 6;
    const int wm   = wid & 1;
    const int wn   = wid >> 1;
    const int rlow = lane & 15;
    const int c    = lane >> 4;

    f32x4 acc[4][4];
    #pragma unroll
    for (int mi = 0; mi < 4; ++mi)
        #pragma unroll
        for (int ni = 0; ni < 4; ++ni)
            acc[mi][ni] = {0.f, 0.f, 0.f, 0.f};

    // stage 1: K=64, one barrier pair
    {
        #pragma unroll
        for (int r = 0; r < 2; ++r) {
            const int i = r * 512 + tid;
            const int row = i >> 3;
            const int cl  = (i & 7) ^ (row & 7);
            __builtin_amdgcn_global_load_lds(
                GLP(x_bf + (size_t)(row0 + row * rs) * 64 + cl * 8),
                LDSP(As + i * 8), 16, 0, 0);
        }
        #pragma unroll
        for (int r = 0; r < 4; ++r) {
            const int i = r * 512 + tid;
            const int row = i >> 3;
            const int cl  = (i & 7) ^ (row & 7);
            __builtin_amdgcn_global_load_lds(
                GLP(W1T + (size_t)row * 64 + cl * 8),
                LDSP(Bs + i * 8), 16, 0, 0);
        }
        __syncthreads();
        #pragma unroll
        for (int k0 = 0; k0 < 64; k0 += 32) {
            short8 af[4], bfr[4];
            #pragma unroll
            for (int mi = 0; mi < 4; ++mi) {
                const int row  = wm * 64 + mi * 16 + rlow;
                const int phys = ((k0 >> 3) + c) ^ (row & 7);
                af[mi] = *(const short8*)((const char*)As + row * 128 + phys * 16);
            }
            #pragma unroll
            for (int ni = 0; ni < 4; ++ni) {
                const int row  = wn * 64 + ni * 16 + rlow;
                const int phys = ((k0 >> 3) + c) ^ (row & 7);
                bfr[ni] = *(const short8*)((const char*)Bs + row * 128 + phys * 16);
            }
            #pragma unroll
            for (int mi = 0; mi < 4; ++mi)
                #pragma unroll
                for (int ni = 0; ni < 4; ++ni)
                    acc[mi][ni] = __builtin_amdgcn_mfma_f32_16x16x32_bf16(
                        af[mi], bfr[ni], acc[mi][ni], 0, 0, 0);
        }
        __syncthreads();
        #pragma unroll
        for (int ni = 0; ni < 4; ++ni) {
            const int col = wn * 64 + ni * 16 + rlow;
            const float bv = b1[col];
            #pragma unroll
            for (int q = 0; q < 4; ++q)
                #pragma unroll
                for (int mi = 0; mi < 4; ++mi) {
                    const int row = wm * 64 + mi * 16 + c * 4 + q;
                    const int byte = (row * 512 + col * 2) ^ ((row & 7) << 4);
                    *(unsigned short*)((char*)I + byte) = f2bf(fmaxf(acc[mi][ni][q] + bv, 0.f));
                }
        }
        __syncthreads();
    }

    // stage 2: K=256, 2 x K=128 staging
    #pragma unroll
    for (int mi = 0; mi < 4; ++mi)
        #pragma unroll
        for (int ni = 0; ni < 4; ++ni)
            acc[mi][ni] = {0.f, 0.f, 0.f, 0.f};

    for (int half = 0; half < 2; ++half) {
        const int k0b = half * 128;
        #pragma unroll
        for (int r = 0; r < 8; ++r) {
            const int i = r * 512 + tid;
            const int row = i >> 4;
            const int cl  = (i & 15) ^ (row & 7);
            __builtin_amdgcn_global_load_lds(
                GLP(W2T + (size_t)row * 256 + k0b + cl * 8),
                LDSP(Bs + i * 8), 16, 0, 0);
        }
        __syncthreads();
        #pragma unroll
        for (int k0l = 0; k0l < 128; k0l += 32) {
            short8 af[4], bfr[4];
            #pragma unroll
            for (int mi = 0; mi < 4; ++mi) {
                const int row = wm * 64 + mi * 16 + rlow;
                const int off = (row * 512 + (k0b + k0l) * 2 + c * 16) ^ ((row & 7) << 4);
                af[mi] = *(const short8*)((const char*)I + off);
            }
            #pragma unroll
            for (int ni = 0; ni < 4; ++ni) {
                const int row  = wn * 64 + ni * 16 + rlow;
                const int phys = ((k0l >> 3) + c) ^ (row & 7);
                bfr[ni] = *(const short8*)((const char*)Bs + row * 256 + phys * 16);
            }
            #pragma unroll
            for (int mi = 0; mi < 4; ++mi)
                #pragma unroll
                for (int ni = 0; ni < 4; ++ni)
                    acc[mi][ni] = __builtin_amdgcn_mfma_f32_16x16x32_bf16(
                        af[mi], bfr[ni], acc[mi][ni], 0, 0, 0);
        }
        __syncthreads();
    }
    #pragma unroll
    for (int ni = 0; ni < 4; ++ni) {
        const int col = wn * 64 + ni * 16 + rlow;
        const float bv = b2[col];
        #pragma unroll
        for (int q = 0; q < 4; ++q)
            #pragma unroll
            for (int mi = 0; mi < 4; ++mi) {
                const int row = wm * 64 + mi * 16 + c * 4 + q;
                const int byte = (row * 512 + col * 2) ^ ((row & 7) << 4);
                *(unsigned short*)((char*)I + byte) = f2bf(fmaxf(acc[mi][ni][q] + bv, 0.f));
            }
    }
    __syncthreads();

    // stage 3: N=192
    f32x4 a3[4][3];
    #pragma unroll
    for (int mi = 0; mi < 4; ++mi)
        #pragma unroll
        for (int ni = 0; ni < 3; ++ni)
            a3[mi][ni] = {0.f, 0.f, 0.f, 0.f};

    for (int half = 0; half < 2; ++half) {
        const int k0b = half * 128;
        #pragma unroll
        for (int r = 0; r < 6; ++r) {
            const int i = r * 512 + tid;
            const int row = i >> 4;
            const int cl  = (i & 15) ^ (row & 7);
            __builtin_amdgcn_global_load_lds(
                GLP(W3T + (size_t)row * 256 + k0b + cl * 8),
                LDSP(Bs + i * 8), 16, 0, 0);
        }
        __syncthreads();
        #pragma unroll
        for (int k0l = 0; k0l < 128; k0l += 32) {
            short8 af[4], bfr[3];
            #pragma unroll
            for (int mi = 0; mi < 4; ++mi) {
                const int row = wm * 64 + mi * 16 + rlow;
                const int off = (row * 512 + (k0b + k0l) * 2 + c * 16) ^ ((row & 7) << 4);
                af[mi] = *(const short8*)((const char*)I + off);
            }
            #pragma unroll
            for (int ni = 0; ni < 3; ++ni) {
                const int row  = wn * 48 + ni * 16 + rlow;
                const int phys = ((k0l >> 3) + c) ^ (row & 7);
                bfr[ni] = *(const short8*)((const char*)Bs + row * 256 + phys * 16);
            }
            #pragma unroll
            for (int mi = 0; mi < 4; ++mi)
                #pragma unroll
                for (int ni = 0; ni < 3; ++ni)
                    a3[mi][ni] = __builtin_amdgcn_mfma_f32_16x16x32_bf16(
                        af[mi], bfr[ni], a3[mi][ni], 0, 0, 0);
        }
        __syncthreads();
    }
    #pragma unroll
    for (int ni = 0; ni < 3; ++ni) {
        const int col = wn * 48 + ni * 16 + rlow;
        #pragma unroll
        for (int mi = 0; mi < 4; ++mi)
            #pragma unroll
            for (int q = 0; q < 4; ++q) {
                const int row = row0 + (wm * 64 + mi * 16 + c * 4 + q) * rs;
                y[(size_t)row * 256 + 64 + col] = a3[mi][ni][q];
            }
    }
}

// ===========================================================================
// Launch C: ffu (0..1023) + bigbt (1024..1535) + cK4 (1536) + y0g (1537..1540)
// ===========================================================================
__global__ __launch_bounds__(512) void midC(
    const __hip_bfloat16* __restrict__ x_bf,
    const __hip_bfloat16* __restrict__ u_bf,
    const __hip_bfloat16* __restrict__ Wx1T, const float* __restrict__ bx1,
    const __hip_bfloat16* __restrict__ Wx2T, const float* __restrict__ bx2,
    const __hip_bfloat16* __restrict__ Wx3T,
    const __hip_bfloat16* __restrict__ Wu1T, const float* __restrict__ bu1,
    const __hip_bfloat16* __restrict__ Wu2T,
    float* __restrict__ y, __hip_bfloat16* __restrict__ vout,
    const float* __restrict__ WB, const float* __restrict__ WBW,
    const float* __restrict__ WBW2, const float* __restrict__ WBW3,
    __hip_bfloat16* __restrict__ T4,
    const float* __restrict__ bK, const float* __restrict__ WK,
    const float* __restrict__ W2f, const float* __restrict__ W3f,
    float* __restrict__ cK4)
{
    __shared__ __align__(16) char smem[147456];
    const int tid = threadIdx.x;

    if (blockIdx.x >= 1024) {
        if (blockIdx.x < 1536) {
            const int o = (blockIdx.x - 1024) * 512 + tid;
            const int n = o >> 10;
            const int rem = o & 1023;
            const int j = rem >> 8, k = rem & 255;
            const float* src = (j == 0) ? WB : (j == 1) ? WBW : (j == 2) ? WBW2 : WBW3;
            ((unsigned short*)T4)[o] = f2bf(src[(size_t)k * 256 + n]);
        } else if (blockIdx.x == 1536) {
            if (tid < 256) {
                const int col = tid;
                float s = bK[col];
                for (int k = 0; k < 256; ++k)
                    s += bK[k] * (WK[(size_t)k * 256 + col] + W2f[(size_t)k * 256 + col]
                                  + W3f[(size_t)k * 256 + col]);
                cK4[col] = s;
            }
        } else {
            // y0g: ffx on the 512 t=0 rows (strided rs=256)
            const int base = (blockIdx.x - 1537) * 128;      // batch start
            ffx_impl(x_bf, Wx1T, bx1, Wx2T, bx2, Wx3T, y,
                     base * 256, 256, smem, tid);
        }
        return;
    }

    // ---- ffu: stage1 K=64 then N=192 final
    __hip_bfloat16* I  = (__hip_bfloat16*)smem;
    __hip_bfloat16* Bs = (__hip_bfloat16*)(smem + 65536);
    __hip_bfloat16* As = (__hip_bfloat16*)(smem + 131072);

    const int lane = tid & 63;
    const int wid  = tid >> 6;
    const int wm   = wid & 1;
    const int wn   = wid >> 1;
    const int row0 = blockIdx.x * 128;
    const int rlow = lane & 15;
    const int c    = lane >> 4;

    f32x4 acc[4][4];
    #pragma unroll
    for (int mi = 0; mi < 4; ++mi)
        #pragma unroll
        for (int ni = 0; ni < 4; ++ni)
            acc[mi][ni] = {0.f, 0.f, 0.f, 0.f};

    {
        #pragma unroll
        for (int r = 0; r < 2; ++r) {
            const int i = r * 512 + tid;
            const int row = i >> 3;
            const int cl  = (i & 7) ^ (row & 7);
            __builtin_amdgcn_global_load_lds(
                GLP(u_bf + (size_t)(row0 + row) * 64 + cl * 8),
                LDSP(As + i * 8), 16, 0, 0);
        }
        #pragma unroll
        for (int r = 0; r < 4; ++r) {
            const int i = r * 512 + tid;
            const int row = i >> 3;
            const int cl  = (i & 7) ^ (row & 7);
            __builtin_amdgcn_global_load_lds(
                GLP(Wu1T + (size_t)row * 64 + cl * 8),
                LDSP(Bs + i * 8), 16, 0, 0);
        }
        __syncthreads();
        #pragma unroll
        for (int k0 = 0; k0 < 64; k0 += 32) {
            short8 af[4], bfr[4];
            #pragma unroll
            for (int mi = 0; mi < 4; ++mi) {
                const int row  = wm * 64 + mi * 16 + rlow;
                const int phys = ((k0 >> 3) + c) ^ (row & 7);
                af[mi] = *(const short8*)((const char*)As + row * 128 + phys * 16);
            }
            #pragma unroll
            for (int ni = 0; ni < 4; ++ni) {
                const int row  = wn * 64 + ni * 16 + rlow;
                const int phys = ((k0 >> 3) + c) ^ (row & 7);
                bfr[ni] = *(const short8*)((const char*)Bs + row * 128 + phys * 16);
            }
            #pragma unroll
            for (int mi = 0; mi < 4; ++mi)
                #pragma unroll
                for (int ni = 0; ni < 4; ++ni)
                    acc[mi][ni] = __builtin_amdgcn_mfma_f32_16x16x32_bf16(
                        af[mi], bfr[ni], acc[mi][ni], 0, 0, 0);
        }
        __syncthreads();
        #pragma unroll
        for (int ni = 0; ni < 4; ++ni) {
            const int col = wn * 64 + ni * 16 + rlow;
            const float bv = bu1[col];
            #pragma unroll
            for (int q = 0; q < 4; ++q)
                #pragma unroll
                for (int mi = 0; mi < 4; ++mi) {
                    const int row = wm * 64 + mi * 16 + c * 4 + q;
                    const int byte = (row * 512 + col * 2) ^ ((row & 7) << 4);
                    *(unsigned short*)((char*)I + byte) = f2bf(fmaxf(acc[mi][ni][q] + bv, 0.f));
                }
        }
        __syncthreads();
    }

    f32x4 a3[4][3];
    #pragma unroll
    for (int mi = 0; mi < 4; ++mi)
        #pragma unroll
        for (int ni = 0; ni < 3; ++ni)
            a3[mi][ni] = {0.f, 0.f, 0.f, 0.f};

    for (int half = 0; half < 2; ++half) {
        const int k0b = half * 128;
        #pragma unroll
        for (int r = 0; r < 6; ++r) {
            const int i = r * 512 + tid;
            const int row = i >> 4;
            const int cl  = (i & 15) ^ (row & 7);
            __builtin_amdgcn_global_load_lds(
                GLP(Wu2T + (size_t)row * 256 + k0b + cl * 8),
                LDSP(Bs + i * 8), 16, 0, 0);
        }
        __syncthreads();
        #pragma unroll
        for (int k0l = 0; k0l < 128; k0l += 32) {
            short8 af[4], bfr[3];
            #pragma unroll
            for (int mi = 0; mi < 4; ++mi) {
                const int row = wm * 64 + mi * 16 + rlow;
                const int off = (row * 512 + (k0b + k0l) * 2 + c * 16) ^ ((row & 7) << 4);
                af[mi] = *(const short8*)((const char*)I + off);
            }
            #pragma unroll
            for (int ni = 0; ni < 3; ++ni) {
                const int row  = wn * 48 + ni * 16 + rlow;
                const int phys = ((k0l >> 3) + c) ^ (row & 7);
                bfr[ni] = *(const short8*)((const char*)Bs + row * 256 + phys * 16);
            }
            #pragma unroll
            for (int mi = 0; mi < 4; ++mi)
                #pragma unroll
                for (int ni = 0; ni < 3; ++ni)
                    a3[mi][ni] = __builtin_amdgcn_mfma_f32_16x16x32_bf16(
                        af[mi], bfr[ni], a3[mi][ni], 0, 0, 0);
        }
        __syncthreads();
    }
    #pragma unroll
    for (int ni = 0; ni < 3; ++ni) {
        const int col = wn * 48 + ni * 16 + rlow;
        #pragma unroll
        for (int mi = 0; mi < 4; ++mi)
            #pragma unroll
            for (int q = 0; q < 4; ++q) {
                const int row = row0 + wm * 64 + mi * 16 + c * 4 + q;
                ((unsigned short*)vout)[(size_t)row * 192 + col] = f2bf(a3[mi][ni][q]);
            }
    }
}

// ===========================================================================
// Launch D: d4g (blocks 0..2047) + stashk (2048..2559).
// ===========================================================================
__global__ __launch_bounds__(256) void d4gS(
    const __hip_bfloat16* __restrict__ u_bf, const __hip_bfloat16* __restrict__ v,
    const __hip_bfloat16* __restrict__ WBT4, const float* __restrict__ cK4,
    float* __restrict__ yp,
    const __hip_bfloat16* __restrict__ WBT, const float* __restrict__ bK,
    float* __restrict__ stash)
{
    __shared__ __align__(16) __hip_bfloat16 As[132 * 32];
    __shared__ __align__(16) __hip_bfloat16 Bs[4][128 * 32];

    const int tid  = threadIdx.x;

    if (blockIdx.x >= 2048) {
        float* uuL = (float*)As;
        const int b = blockIdx.x - 2048;
        #pragma unroll
        for (int p = 0; p < 3; ++p) {
            float val;
            if (tid < 64) val = bf2f(((const unsigned short*)u_bf)[((size_t)b * 256 + p) * 64 + tid]);
            else          val = bf2f(((const unsigned short*)v)[((size_t)b * 256 + p) * 192 + tid - 64]);
            uuL[p * 256 + tid] = val;
        }
        __syncthreads();
        const int col = tid;
        float a0 = bK[col], a1 = a0, a2 = a0;
        for (int k = 0; k < 256; ++k) {
            const float w = bf2f(((const unsigned short*)WBT)[(size_t)col * 256 + k]);
            a0 += uuL[0 * 256 + k] * w;
            a1 += uuL[1 * 256 + k] * w;
            a2 += uuL[2 * 256 + k] * w;
        }
        stash[((size_t)b * 3 + 0) * 256 + col] = a0;
        stash[((size_t)b * 3 + 1) * 256 + col] = a1;
        stash[((size_t)b * 3 + 2) * 256 + col] = a2;
        return;
    }

    const int lane = tid & 63;
    const int wid  = tid >> 6;
    const int wm   = wid & 1;
    const int wn   = wid >> 1;
    const int row0 = (blockIdx.x >> 1) * 128;
    const int col0 = (blockIdx.x & 1) * 128;
    const int rlow = lane & 15;
    const int c    = lane >> 4;

    f32x4 acc[4][4];
    #pragma unroll
    for (int mi = 0; mi < 4; ++mi)
        #pragma unroll
        for (int ni = 0; ni < 4; ++ni)
            acc[mi][ni] = {0.f, 0.f, 0.f, 0.f};

    for (int kl = 0; kl < 256; kl += 32) {
        const __hip_bfloat16* Ab; int Al, kk;
        if (kl < 64) { Ab = u_bf; Al = 64;  kk = kl; }
        else         { Ab = v;    Al = 192; kk = kl - 64; }

        #pragma unroll
        for (int r = 0; r < 3; ++r) {
            const int i = r * 256 + tid;
            if (i < 528) {
                const int row = i >> 2;
                const int cl  = (i & 3) ^ ((row >> 1) & 3);
                int srow = row0 - 4 + row;
                if (srow < 0) srow = 0;
                __builtin_amdgcn_global_load_lds(
                    GLP(Ab + (size_t)srow * Al + kk + cl * 8),
                    LDSP(As + i * 8), 16, 0, 0);
            }
        }
        #pragma unroll
        for (int r = 0; r < 8; ++r) {
            const int i = r * 256 + tid;
            const int j = i >> 9;
            const int s = i & 511;
            const int row = s >> 2;
            const int cl  = (s & 3) ^ ((row >> 1) & 3);
            __builtin_amdgcn_global_load_lds(
                GLP(WBT4 + (size_t)(col0 + row) * 1024 + j * 256 + kl + cl * 8),
                LDSP(&Bs[0][0] + i * 8), 16, 0, 0);
        }
        __syncthreads();

        #pragma unroll
        for (int j = 0; j < 4; ++j) {
            short8 bfr[4];
            #pragma unroll
            for (int ni = 0; ni < 4; ++ni) {
                const int row  = wn * 64 + ni * 16 + rlow;
                const int phys = c ^ ((row >> 1) & 3);
                bfr[ni] = *(const short8*)((const char*)Bs[j] + row * 64 + phys * 16);
            }
            #pragma unroll
            for (int mi = 0; mi < 4; ++mi) {
                const int prow = wm * 64 + mi * 16 + rlow + 3 - j;
                const int phys = c ^ ((prow >> 1) & 3);
                const short8 af = *(const short8*)((const char*)As + prow * 64 + phys * 16);
                #pragma unroll
                for (int ni = 0; ni < 4; ++ni)
                    acc[mi][ni] = __builtin_amdgcn_mfma_f32_16x16x32_bf16(
                        af, bfr[ni], acc[mi][ni], 0, 0, 0);
            }
        }
        __syncthreads();
    }

    const int q4 = lane >> 4;
    #pragma unroll
    for (int ni = 0; ni < 4; ++ni) {
        const int col = col0 + wn * 64 + ni * 16 + rlow;
        const float bv = cK4[col];
        #pragma unroll
        for (int mi = 0; mi < 4; ++mi) {
            #pragma unroll
            for (int q = 0; q < 4; ++q) {
                const int row = row0 + wm * 64 + mi * 16 + q4 * 4 + q;
                if ((row & 255) >= 4)
                    yp[(size_t)row * 256 + col] = acc[mi][ni][q] + bv;
            }
        }
    }
}

// ---------------------------------------------------------------------------
// gather hi/lo bf16 B-fragments of a 256x256 fp32 matrix
// ---------------------------------------------------------------------------
static __device__ __forceinline__ void gather_frags(
    const float* __restrict__ M, int col0, int rlow, int kg,
    short8 (&wh)[2][8], short8 (&wl)[2][8])
{
    #pragma unroll
    for (int tile = 0; tile < 2; ++tile) {
        const int col = col0 + tile * 16 + rlow;
        for (int kc = 0; kc < 8; ++kc) {
            const int k0 = kc * 32 + kg * 8;
            short8 h, l;
            for (int i = 0; i < 8; ++i) {
                const float w = M[(size_t)(k0 + i) * 256 + col];
                const unsigned short hb = f2bf(w);
                h[i] = (short)hb;
                l[i] = (short)f2bf(w - bf2f(hb));
            }
            wh[tile][kc] = h;
            wl[tile][kc] = l;
        }
    }
}

// ===========================================================================
// Launch E: blocks 0..127 = scan4 (r15 body) ; blocks 128..1151 = full ffx
// (redundantly rewrites t=0 rows with identical values — benign).
// Shared 144KB LDS arena unioned between the two roles.
// ===========================================================================
__global__ __launch_bounds__(512, 1) void scanFX(
    const float* __restrict__ WK, const float* __restrict__ W4,
    const float* __restrict__ stash,
    const float* __restrict__ y, float* __restrict__ yp,
    const __hip_bfloat16* __restrict__ x_bf,
    const __hip_bfloat16* __restrict__ Wx1T, const float* __restrict__ bx1,
    const __hip_bfloat16* __restrict__ Wx2T, const float* __restrict__ bx2,
    const __hip_bfloat16* __restrict__ Wx3T,
    float* __restrict__ yob)
{
    __shared__ __align__(16) char smem[147456];
    const int tid  = threadIdx.x;

    if (blockIdx.x >= 128) {
        ffx_impl(x_bf, Wx1T, bx1, Wx2T, bx2, Wx3T, yob,
                 (blockIdx.x - 128) * 128, 1, smem, tid);
        return;
    }

    // ---- scan4 ----
    typedef __hip_bfloat16 CB[2][16 * 256];
    CB* cbuf = (CB*)smem;                       // [2][2][16*256] = 64KB

    const int lane = tid & 63;
    const int wid  = tid >> 6;
    const int b0   = blockIdx.x * 4;
    const int col0 = wid * 32;
    const int rlow = lane & 15;
    const int kg   = lane >> 4;
    const int rswz = (rlow & 7) << 4;

    #pragma unroll
    for (int e = 0; e < 2; ++e) {
        const int idx = tid * 2 + e;
        const int br  = idx >> 8;
        const int cc  = idx & 255;
        const float v = y[(size_t)(b0 + br) * 65536 + cc];
        yp[(size_t)(b0 + br) * 65536 + cc] = v;
        const unsigned short hb = f2bf(v);
        const unsigned short lb = f2bf(v - bf2f(hb));
        const int byte = (br * 512 + cc * 2) ^ ((br & 7) << 4);
        *(unsigned short*)((char*)&cbuf[0][0][0] + byte) = hb;
        *(unsigned short*)((char*)&cbuf[0][1][0] + byte) = lb;
    }
    __syncthreads();

    short8 wh[2][8], wl[2][8];
    gather_frags(WK, col0, rlow, kg, wh, wl);

    for (int p = 1; p < 4; ++p) {
        f32x4 aHH[2], aHL[2], aLH[2], bHH[2], bHL[2], bLH[2];
        #pragma unroll
        for (int tile = 0; tile < 2; ++tile) {
            aHH[tile] = {0.f,0.f,0.f,0.f}; aHL[tile] = {0.f,0.f,0.f,0.f}; aLH[tile] = {0.f,0.f,0.f,0.f};
            bHH[tile] = {0.f,0.f,0.f,0.f}; bHL[tile] = {0.f,0.f,0.f,0.f}; bLH[tile] = {0.f,0.f,0.f,0.f};
        }
        const char* hbase = (const char*)&cbuf[0][0][0];
        const char* lbase = (const char*)&cbuf[0][1][0];
        #pragma unroll
        for (int kc = 0; kc < 4; ++kc) {
            const int off = (rlow * 512 + kg * 16 + kc * 64) ^ rswz;
            const short8 ah = *(const short8*)(hbase + off);
            const short8 al = *(const short8*)(lbase + off);
            aHH[0] = __builtin_amdgcn_mfma_f32_16x16x32_bf16(ah, wh[0][kc], aHH[0], 0, 0, 0);
            aHH[1] = __builtin_amdgcn_mfma_f32_16x16x32_bf16(ah, wh[1][kc], aHH[1], 0, 0, 0);
            aHL[0] = __builtin_amdgcn_mfma_f32_16x16x32_bf16(ah, wl[0][kc], aHL[0], 0, 0, 0);
            aHL[1] = __builtin_amdgcn_mfma_f32_16x16x32_bf16(ah, wl[1][kc], aHL[1], 0, 0, 0);
            aLH[0] = __builtin_amdgcn_mfma_f32_16x16x32_bf16(al, wh[0][kc], aLH[0], 0, 0, 0);
            aLH[1] = __builtin_amdgcn_mfma_f32_16x16x32_bf16(al, wh[1][kc], aLH[1], 0, 0, 0);
        }
        #pragma unroll
        for (int kc = 4; kc < 8; ++kc) {
            const int off = (rlow * 512 + kg * 16 + kc * 64) ^ rswz;
            const short8 ah = *(const short8*)(hbase + off);
            const short8 al = *(const short8*)(lbase + off);
            bHH[0] = __builtin_amdgcn_mfma_f32_16x16x32_bf16(ah, wh[0][kc], bHH[0], 0, 0, 0);
            bHH[1] = __builtin_amdgcn_mfma_f32_16x16x32_bf16(ah, wh[1][kc], bHH[1], 0, 0, 0);
            bHL[0] = __builtin_amdgcn_mfma_f32_16x16x32_bf16(ah, wl[0][kc], bHL[0], 0, 0, 0);
            bHL[1] = __builtin_amdgcn_mfma_f32_16x16x32_bf16(ah, wl[1][kc], bHL[1], 0, 0, 0);
            bLH[0] = __builtin_amdgcn_mfma_f32_16x16x32_bf16(al, wh[0][kc], bLH[0], 0, 0, 0);
            bLH[1] = __builtin_amdgcn_mfma_f32_16x16x32_bf16(al, wh[1][kc], bLH[1], 0, 0, 0);
        }
        __builtin_amdgcn_sched_barrier(0);
        asm volatile("s_waitcnt lgkmcnt(0)" ::: "memory");
        __builtin_amdgcn_s_barrier();
        __builtin_amdgcn_sched_barrier(0);

        if (kg == p - 1) {
            #pragma unroll
            for (int tile = 0; tile < 2; ++tile) {
                const int col = col0 + tile * 16 + rlow;
                #pragma unroll
                for (int q = 0; q < 4; ++q) {
                    const float cv = stash[((size_t)(b0 + q) * 3 + (p - 1)) * 256 + col];
                    const float yv = (aHH[tile][q] + bHH[tile][q]) + (aHL[tile][q] + bHL[tile][q])
                                   + (aLH[tile][q] + bLH[tile][q]) + cv;
                    const int wr = p * 4 + q;
                    const unsigned short hb = f2bf(yv);
                    const unsigned short lb = f2bf(yv - bf2f(hb));
                    const int byte = (wr * 512 + col * 2) ^ ((wr & 7) << 4);
                    *(unsigned short*)((char*)&cbuf[0][0][0] + byte) = hb;
                    *(unsigned short*)((char*)&cbuf[0][1][0] + byte) = lb;
                    yp[(size_t)(b0 + q) * 65536 + (size_t)p * 256 + col] = yv;
                }
            }
        }
        __builtin_amdgcn_sched_barrier(0);
        asm volatile("s_waitcnt lgkmcnt(0)" ::: "memory");
        __builtin_amdgcn_s_barrier();
        __builtin_amdgcn_sched_barrier(0);
    }

    gather_frags(W4, col0, rlow, kg, wh, wl);

    float dv[2][4];
    #pragma unroll
    for (int tile = 0; tile < 2; ++tile) {
        const int col = col0 + tile * 16 + rlow;
        #pragma unroll
        for (int q = 0; q < 4; ++q)
            dv[tile][q] = yp[(size_t)(b0 + q) * 65536 + (size_t)(4 + kg) * 256 + col];
    }

    int cur = 0;
    for (int s = 0; s < 63; ++s) {
        const int tb = 4 + s * 4;

        float dn[2][4];
        if (s < 62) {
            #pragma unroll
            for (int tile = 0; tile < 2; ++tile) {
                const int col = col0 + tile * 16 + rlow;
                #pragma unroll
                for (int q = 0; q < 4; ++q)
                    dn[tile][q] = yp[(size_t)(b0 + q) * 65536
                                     + (size_t)(tb + 4 + kg) * 256 + col];
            }
        }

        f32x4 aHH[2], aHL[2], aLH[2], bHH[2], bHL[2], bLH[2];
        #pragma unroll
        for (int tile = 0; tile < 2; ++tile) {
            aHH[tile] = {0.f,0.f,0.f,0.f}; aHL[tile] = {0.f,0.f,0.f,0.f}; aLH[tile] = {0.f,0.f,0.f,0.f};
            bHH[tile] = {0.f,0.f,0.f,0.f}; bHL[tile] = {0.f,0.f,0.f,0.f}; bLH[tile] = {0.f,0.f,0.f,0.f};
        }
        const char* hbase = (const char*)&cbuf[cur][0][0];
        const char* lbase = (const char*)&cbuf[cur][1][0];
        #pragma unroll
        for (int kc = 0; kc < 4; ++kc) {
            const int off = (rlow * 512 + kg * 16 + kc * 64) ^ rswz;
            const short8 ah = *(const short8*)(hbase + off);
            const short8 al = *(const short8*)(lbase + off);
            aHH[0] = __builtin_amdgcn_mfma_f32_16x16x32_bf16(ah, wh[0][kc], aHH[0], 0, 0, 0);
            aHH[1] = __builtin_amdgcn_mfma_f32_16x16x32_bf16(ah, wh[1][kc], aHH[1], 0, 0, 0);
            aHL[0] = __builtin_amdgcn_mfma_f32_16x16x32_bf16(ah, wl[0][kc], aHL[0], 0, 0, 0);
            aHL[1] = __builtin_amdgcn_mfma_f32_16x16x32_bf16(ah, wl[1][kc], aHL[1], 0, 0, 0);
            aLH[0] = __builtin_amdgcn_mfma_f32_16x16x32_bf16(al, wh[0][kc], aLH[0], 0, 0, 0);
            aLH[1] = __builtin_amdgcn_mfma_f32_16x16x32_bf16(al, wh[1][kc], aLH[1], 0, 0, 0);
        }
        #pragma unroll
        for (int kc = 4; kc < 8; ++kc) {
            const int off = (rlow * 512 + kg * 16 + kc * 64) ^ rswz;
            const short8 ah = *(const short8*)(hbase + off);
            const short8 al = *(const short8*)(lbase + off);
            bHH[0] = __builtin_amdgcn_mfma_f32_16x16x32_bf16(ah, wh[0][kc], bHH[0], 0, 0, 0);
            bHH[1] = __builtin_amdgcn_mfma_f32_16x16x32_bf16(ah, wh[1][kc], bHH[1], 0, 0, 0);
            bHL[0] = __builtin_amdgcn_mfma_f32_16x16x32_bf16(ah, wl[0][kc], bHL[0], 0, 0, 0);
            bHL[1] = __builtin_amdgcn_mfma_f32_16x16x32_bf16(ah, wl[1][kc], bHL[1], 0, 0, 0);
            bLH[0] = __builtin_amdgcn_mfma_f32_16x16x32_bf16(al, wh[0][kc], bLH[0], 0, 0, 0);
            bLH[1] = __builtin_amdgcn_mfma_f32_16x16x32_bf16(al, wh[1][kc], bLH[1], 0, 0, 0);
        }

        char* whb = (char*)&cbuf[cur ^ 1][0][0];
        char* wlb = (char*)&cbuf[cur ^ 1][1][0];
        #pragma unroll
        for (int tile = 0; tile < 2; ++tile) {
            const int col = col0 + tile * 16 + rlow;
            #pragma unroll
            for (int q = 0; q < 4; ++q) {
                const int row = kg * 4 + q;
                const float yv = (aHH[tile][q] + bHH[tile][q]) + (aHL[tile][q] + bHL[tile][q])
                               + (aLH[tile][q] + bLH[tile][q]) + dv[tile][q];
                const unsigned short hb = f2bf(yv);
                const unsigned short lb = f2bf(yv - bf2f(hb));
                const int byte = (row * 512 + col * 2) ^ ((row & 7) << 4);
                *(unsigned short*)(whb + byte) = hb;
                *(unsigned short*)(wlb + byte) = lb;
                yp[(size_t)(b0 + q) * 65536 + (size_t)(tb + kg) * 256 + col] = yv;
            }
        }
        if (s < 62) {
            #pragma unroll
            for (int tile = 0; tile < 2; ++tile)
                #pragma unroll
                for (int q = 0; q < 4; ++q)
                    dv[tile][q] = dn[tile][q];
        }

        __builtin_amdgcn_sched_barrier(0);
        asm volatile("s_waitcnt lgkmcnt(0)" ::: "memory");
        __builtin_amdgcn_s_barrier();
        __builtin_amdgcn_sched_barrier(0);
        cur ^= 1;
    }
}

// ---------------------------------------------------------------------------
extern "C" void kernel_launch(void* const* d_in, const int* in_sizes, int n_in,
                              void* d_out, int out_size, void* d_ws, size_t ws_size,
                              hipStream_t stream)
{
    const float* x   = (const float*)d_in[0];
    const float* u   = (const float*)d_in[1];
    const float* Wx1 = (const float*)d_in[2];
    const float* bx1 = (const float*)d_in[3];
    const float* Wx2 = (const float*)d_in[4];
    const float* bx2 = (const float*)d_in[5];
    const float* Wx3 = (const float*)d_in[6];
    const float* Wu1 = (const float*)d_in[7];
    const float* bu1 = (const float*)d_in[8];
    const float* Wu2 = (const float*)d_in[9];
    const float* WB  = (const float*)d_in[10];
    const float* WK  = (const float*)d_in[11];
    const float* bK  = (const float*)d_in[12];

    float* y  = (float*)d_out;
    float* yp = y + (size_t)MM * 256;

    char* ws = (char*)d_ws;
    __hip_bfloat16* x_bf = (__hip_bfloat16*)(ws);
    __hip_bfloat16* u_bf = (__hip_bfloat16*)(ws + 16777216);
    __hip_bfloat16* wTb  = (__hip_bfloat16*)(ws + 33554432);
    __hip_bfloat16* Wx1T = wTb;
    __hip_bfloat16* Wx2T = wTb + 16384;
    __hip_bfloat16* Wx3T = wTb + 81920;
    __hip_bfloat16* Wu1T = wTb + 131072;
    __hip_bfloat16* Wu2T = wTb + 147456;
    __hip_bfloat16* WBT  = wTb + 196608;
    __hip_bfloat16* t2   = (__hip_bfloat16*)(ws + 34078720);     // v (M x 192)
    float* W2f   = (float*)(ws + 101187584);
    float* W3f   = (float*)(ws + 101449728);
    float* W4f   = (float*)(ws + 101711872);
    float* WBWf  = (float*)(ws + 101974016);
    float* WBW2f = (float*)(ws + 102236160);
    float* WBW3f = (float*)(ws + 102498304);
    __hip_bfloat16* WBT4 = (__hip_bfloat16*)(ws + 102760448);
    float* cK4   = (float*)(ws + 103284736);
    float* stash = (float*)(ws + 103285760);

    prepA<<<17440, dim3(256), 0, stream>>>(x, u, x_bf, u_bf, y,
        Wx1, Wx2, Wx3, Wu1, Wu2, WB,
        Wx1T, Wx2T, Wx3T, Wu1T, Wu2T, WBT,
        WK, WB, W2f, WBWf);

    {
        G5 L2 = {{W2f, W2f, WBWf, WBWf, nullptr},
                 {WK, W2f, WK, W2f, nullptr},
                 {W3f, W4f, WBW2f, WBW3f, nullptr}};
        wgemm<<<64, dim3(256), 0, stream>>>(L2);
    }

    // C: ffu + bigbt + cK4 + y0g (t=0 rows of x-path)
    midC<<<1541, dim3(512), 0, stream>>>(x_bf, u_bf,
        Wx1T, bx1, Wx2T, bx2, Wx3T, Wu1T, bu1, Wu2T,
        y, t2,
        WB, WBWf, WBW2f, WBW3f, WBT4,
        bK, WK, W2f, W3f, cK4);

    // D: d4g + stashk
    d4gS<<<2560, dim3(256), 0, stream>>>(u_bf, t2, WBT4, cK4, yp, WBT, bK, stash);

    // E: scan4 (blocks 0..127) overlapped with full ffx (blocks 128..1151)
    scanFX<<<1152, dim3(512), 0, stream>>>(WK, W4f, stash, y, yp,
        x_bf, Wx1T, bx1, Wx2T, bx2, Wx3T, y);
}

// Round 17
// 402.442 us; speedup vs baseline: 1.0293x; 1.0293x over previous
//
#include <hip/hip_runtime.h>
#include <hip/hip_bf16.h>

#define MM 131072

typedef __attribute__((ext_vector_type(8))) short short8;
typedef __attribute__((ext_vector_type(4))) float f32x4;

#define GLP(p) (const __attribute__((address_space(1))) void*)(p)
#define LDSP(p) (__attribute__((address_space(3))) void*)(p)

static __device__ __forceinline__ unsigned short f2bf(float f) {
    union { float f; unsigned int u; } v; v.f = f;
    unsigned int r = v.u + 0x7FFF + ((v.u >> 16) & 1);  // RNE
    return (unsigned short)(r >> 16);
}
static __device__ __forceinline__ float bf2f(unsigned short h) {
    union { float f; unsigned int u; } v; v.u = ((unsigned int)h) << 16;
    return v.f;
}

// ===========================================================================
// Launch A: prep (conv x/u -> bf16, x->y cols 0..63, 6x W->WT) + wgemm L1
// ===========================================================================
__global__ __launch_bounds__(256) void prepA(
    const float* __restrict__ x, const float* __restrict__ u,
    __hip_bfloat16* __restrict__ xb, __hip_bfloat16* __restrict__ ub,
    float* __restrict__ y,
    const float* __restrict__ W0, const float* __restrict__ W1,
    const float* __restrict__ W2, const float* __restrict__ W3,
    const float* __restrict__ W4, const float* __restrict__ W5,
    __hip_bfloat16* __restrict__ T0, __hip_bfloat16* __restrict__ T1,
    __hip_bfloat16* __restrict__ T2, __hip_bfloat16* __restrict__ T3,
    __hip_bfloat16* __restrict__ T4, __hip_bfloat16* __restrict__ T5,
    const float* __restrict__ WK, const float* __restrict__ WB,
    float* __restrict__ W2f, float* __restrict__ WBWf)
{
    __shared__ __align__(16) float As[16][68];
    __shared__ __align__(16) float Ws[16][64];

    if (blockIdx.x < 16384) {
        int i = blockIdx.x * 256 + threadIdx.x;
        const float* s; __hip_bfloat16* d; int j; bool isx;
        if (i < 2097152) { s = x; d = xb; j = i; isx = true; }
        else             { s = u; d = ub; j = i - 2097152; isx = false; }
        const float4 v = ((const float4*)s)[j];
        union { unsigned short h[4]; uint2 u2; } p;
        p.h[0] = f2bf(v.x); p.h[1] = f2bf(v.y);
        p.h[2] = f2bf(v.z); p.h[3] = f2bf(v.w);
        ((uint2*)d)[j] = p.u2;
        if (isx) {
            const int r = j >> 4, q = j & 15;
            ((float4*)(y + (size_t)r * 256))[q] = v;
        }
    } else if (blockIdx.x < 17408) {
        const int b = blockIdx.x - 16384;
        const float* W; __hip_bfloat16* T; int K, N, i0;
        if      (b < 64)  { W = W0; T = T0; K = 64;  N = 256; i0 = b; }
        else if (b < 320) { W = W1; T = T1; K = 256; N = 256; i0 = b - 64; }
        else if (b < 512) { W = W2; T = T2; K = 256; N = 192; i0 = b - 320; }
        else if (b < 576) { W = W3; T = T3; K = 64;  N = 256; i0 = b - 512; }
        else if (b < 768) { W = W4; T = T4; K = 256; N = 192; i0 = b - 576; }
        else              { W = W5; T = T5; K = 256; N = 256; i0 = b - 768; }
        const int i = i0 * 256 + threadIdx.x;
        if (i < K * N) {
            const int n = i / K, k = i - n * K;
            T[i] = __float2bfloat16(W[(size_t)k * N + n]);
        }
    } else {
        const int tile = blockIdx.x - 17408;
        const int e  = tile >> 4;
        const int tl = tile & 15;
        const float* A = e ? WB : WK;
        const float* W = WK;
        float*       C = e ? WBWf : W2f;
        const int row0 = (tl >> 2) * 64;
        const int col0 = (tl & 3) * 64;
        const int tx = threadIdx.x & 15;
        const int ty = threadIdx.x >> 4;
        float acc[4][4] = {};
        for (int k0 = 0; k0 < 256; k0 += 16) {
            {
                const int kk = threadIdx.x & 15;
                const int r  = threadIdx.x >> 4;
                #pragma unroll
                for (int rr = 0; rr < 4; ++rr)
                    As[kk][r + rr * 16] = A[(size_t)(row0 + r + rr * 16) * 256 + k0 + kk];
            }
            {
                const int n  = threadIdx.x & 63;
                const int kz = threadIdx.x >> 6;
                #pragma unroll
                for (int kq = 0; kq < 4; ++kq) {
                    const int kk = kz + kq * 4;
                    Ws[kk][n] = W[(size_t)(k0 + kk) * 256 + col0 + n];
                }
            }
            __syncthreads();
            #pragma unroll
            for (int kk = 0; kk < 16; ++kk) {
                const float4 a4 = *(const float4*)&As[kk][ty * 4];
                const float4 w4 = *(const float4*)&Ws[kk][tx * 4];
                const float av[4] = {a4.x, a4.y, a4.z, a4.w};
                const float wv[4] = {w4.x, w4.y, w4.z, w4.w};
                #pragma unroll
                for (int i = 0; i < 4; ++i)
                    #pragma unroll
                    for (int j = 0; j < 4; ++j)
                        acc[i][j] += av[i] * wv[j];
            }
            __syncthreads();
        }
        #pragma unroll
        for (int i = 0; i < 4; ++i)
            #pragma unroll
            for (int j = 0; j < 4; ++j)
                C[(size_t)(row0 + ty * 4 + i) * 256 + col0 + tx * 4 + j] = acc[i][j];
    }
}

// ===========================================================================
// Launch B: wgemm L2 (4 GEMMs: W3, W4, WBW2, WBW3)
// ===========================================================================
struct G5 { const float* a[5]; const float* b[5]; float* c[5]; };

__global__ __launch_bounds__(256) void wgemm(G5 P)
{
    __shared__ __align__(16) float As[16][68];
    __shared__ __align__(16) float Ws[16][64];

    const int e  = blockIdx.x >> 4;
    const int tl = blockIdx.x & 15;
    const float* A = P.a[e];
    const float* W = P.b[e];
    float*       C = P.c[e];
    const int row0 = (tl >> 2) * 64;
    const int col0 = (tl & 3) * 64;

    const int tx = threadIdx.x & 15;
    const int ty = threadIdx.x >> 4;

    float acc[4][4] = {};

    for (int k0 = 0; k0 < 256; k0 += 16) {
        {
            const int kk = threadIdx.x & 15;
            const int r  = threadIdx.x >> 4;
            #pragma unroll
            for (int rr = 0; rr < 4; ++rr)
                As[kk][r + rr * 16] = A[(size_t)(row0 + r + rr * 16) * 256 + k0 + kk];
        }
        {
            const int n  = threadIdx.x & 63;
            const int kz = threadIdx.x >> 6;
            #pragma unroll
            for (int kq = 0; kq < 4; ++kq) {
                const int kk = kz + kq * 4;
                Ws[kk][n] = W[(size_t)(k0 + kk) * 256 + col0 + n];
            }
        }
        __syncthreads();
        #pragma unroll
        for (int kk = 0; kk < 16; ++kk) {
            const float4 a4 = *(const float4*)&As[kk][ty * 4];
            const float4 w4 = *(const float4*)&Ws[kk][tx * 4];
            const float av[4] = {a4.x, a4.y, a4.z, a4.w};
            const float wv[4] = {w4.x, w4.y, w4.z, w4.w};
            #pragma unroll
            for (int i = 0; i < 4; ++i)
                #pragma unroll
                for (int j = 0; j < 4; ++j)
                    acc[i][j] += av[i] * wv[j];
        }
        __syncthreads();
    }

    #pragma unroll
    for (int i = 0; i < 4; ++i)
        #pragma unroll
        for (int j = 0; j < 4; ++j)
            C[(size_t)(row0 + ty * 4 + i) * 256 + col0 + tx * 4 + j] = acc[i][j];
}

// ===========================================================================
// Launch C (r15-measured-good): ffx (0..1023) + ffu (1024..2047) +
// bigbt (2048..2559) + cK4 (2560). 512 threads.
// ===========================================================================
__global__ __launch_bounds__(512) void ffC(
    const __hip_bfloat16* __restrict__ x_bf,
    const __hip_bfloat16* __restrict__ u_bf,
    const __hip_bfloat16* __restrict__ Wx1T, const float* __restrict__ bx1,
    const __hip_bfloat16* __restrict__ Wx2T, const float* __restrict__ bx2,
    const __hip_bfloat16* __restrict__ Wx3T,
    const __hip_bfloat16* __restrict__ Wu1T, const float* __restrict__ bu1,
    const __hip_bfloat16* __restrict__ Wu2T,
    float* __restrict__ y, __hip_bfloat16* __restrict__ vout,
    const float* __restrict__ WB, const float* __restrict__ WBW,
    const float* __restrict__ WBW2, const float* __restrict__ WBW3,
    __hip_bfloat16* __restrict__ T4,
    const float* __restrict__ bK, const float* __restrict__ WK,
    const float* __restrict__ W2f, const float* __restrict__ W3f,
    float* __restrict__ cK4)
{
    __shared__ __align__(16) __hip_bfloat16 I[128 * 256];    // 64 KB
    __shared__ __align__(16) __hip_bfloat16 Bs[256 * 128];   // 64 KB
    __shared__ __align__(16) __hip_bfloat16 As[128 * 64];    // 16 KB

    const int tid  = threadIdx.x;

    if (blockIdx.x >= 2048) {
        if (blockIdx.x < 2560) {
            const int o = (blockIdx.x - 2048) * 512 + tid;
            const int n = o >> 10;
            const int rem = o & 1023;
            const int j = rem >> 8, k = rem & 255;
            const float* src = (j == 0) ? WB : (j == 1) ? WBW : (j == 2) ? WBW2 : WBW3;
            ((unsigned short*)T4)[o] = f2bf(src[(size_t)k * 256 + n]);
        } else {
            if (tid < 256) {
                const int col = tid;
                float s = bK[col];
                for (int k = 0; k < 256; ++k)
                    s += bK[k] * (WK[(size_t)k * 256 + col] + W2f[(size_t)k * 256 + col]
                                  + W3f[(size_t)k * 256 + col]);
                cK4[col] = s;
            }
        }
        return;
    }

    const bool isx = blockIdx.x < 1024;
    const __hip_bfloat16* in  = isx ? x_bf : u_bf;
    const __hip_bfloat16* W1T = isx ? Wx1T : Wu1T;
    const float*          b1  = isx ? bx1  : bu1;
    const int lane = tid & 63;
    const int wid  = tid >> 6;
    const int wm   = wid & 1;
    const int wn   = wid >> 1;
    const int row0 = (blockIdx.x & 1023) * 128;
    const int rlow = lane & 15;
    const int c    = lane >> 4;

    f32x4 acc[4][4];
    #pragma unroll
    for (int mi = 0; mi < 4; ++mi)
        #pragma unroll
        for (int ni = 0; ni < 4; ++ni)
            acc[mi][ni] = {0.f, 0.f, 0.f, 0.f};

    // stage 1: K=64 fully staged, 1 barrier pair
    {
        #pragma unroll
        for (int r = 0; r < 2; ++r) {
            const int i = r * 512 + tid;
            const int row = i >> 3;
            const int cl  = (i & 7) ^ (row & 7);
            __builtin_amdgcn_global_load_lds(
                GLP(in + (size_t)(row0 + row) * 64 + cl * 8),
                LDSP(As + i * 8), 16, 0, 0);
        }
        #pragma unroll
        for (int r = 0; r < 4; ++r) {
            const int i = r * 512 + tid;
            const int row = i >> 3;
            const int cl  = (i & 7) ^ (row & 7);
            __builtin_amdgcn_global_load_lds(
                GLP(W1T + (size_t)row * 64 + cl * 8),
                LDSP(Bs + i * 8), 16, 0, 0);
        }
        __syncthreads();
        #pragma unroll
        for (int k0 = 0; k0 < 64; k0 += 32) {
            short8 af[4], bfr[4];
            #pragma unroll
            for (int mi = 0; mi < 4; ++mi) {
                const int row  = wm * 64 + mi * 16 + rlow;
                const int phys = ((k0 >> 3) + c) ^ (row & 7);
                af[mi] = *(const short8*)((const char*)As + row * 128 + phys * 16);
            }
            #pragma unroll
            for (int ni = 0; ni < 4; ++ni) {
                const int row  = wn * 64 + ni * 16 + rlow;
                const int phys = ((k0 >> 3) + c) ^ (row & 7);
                bfr[ni] = *(const short8*)((const char*)Bs + row * 128 + phys * 16);
            }
            #pragma unroll
            for (int mi = 0; mi < 4; ++mi)
                #pragma unroll
                for (int ni = 0; ni < 4; ++ni)
                    acc[mi][ni] = __builtin_amdgcn_mfma_f32_16x16x32_bf16(
                        af[mi], bfr[ni], acc[mi][ni], 0, 0, 0);
        }
        __syncthreads();
        #pragma unroll
        for (int ni = 0; ni < 4; ++ni) {
            const int col = wn * 64 + ni * 16 + rlow;
            const float bv = b1[col];
            #pragma unroll
            for (int q = 0; q < 4; ++q)
                #pragma unroll
                for (int mi = 0; mi < 4; ++mi) {
                    const int row = wm * 64 + mi * 16 + c * 4 + q;
                    const int byte = (row * 512 + col * 2) ^ ((row & 7) << 4);
                    *(unsigned short*)((char*)I + byte) = f2bf(fmaxf(acc[mi][ni][q] + bv, 0.f));
                }
        }
        __syncthreads();
    }

    if (isx) {
        // stage 2: 2 x K=128 staging
        #pragma unroll
        for (int mi = 0; mi < 4; ++mi)
            #pragma unroll
            for (int ni = 0; ni < 4; ++ni)
                acc[mi][ni] = {0.f, 0.f, 0.f, 0.f};

        for (int half = 0; half < 2; ++half) {
            const int k0b = half * 128;
            #pragma unroll
            for (int r = 0; r < 8; ++r) {
                const int i = r * 512 + tid;
                const int row = i >> 4;
                const int cl  = (i & 15) ^ (row & 7);
                __builtin_amdgcn_global_load_lds(
                    GLP(Wx2T + (size_t)row * 256 + k0b + cl * 8),
                    LDSP(Bs + i * 8), 16, 0, 0);
            }
            __syncthreads();
            #pragma unroll
            for (int k0l = 0; k0l < 128; k0l += 32) {
                short8 af[4], bfr[4];
                #pragma unroll
                for (int mi = 0; mi < 4; ++mi) {
                    const int row = wm * 64 + mi * 16 + rlow;
                    const int off = (row * 512 + (k0b + k0l) * 2 + c * 16) ^ ((row & 7) << 4);
                    af[mi] = *(const short8*)((const char*)I + off);
                }
                #pragma unroll
                for (int ni = 0; ni < 4; ++ni) {
                    const int row  = wn * 64 + ni * 16 + rlow;
                    const int phys = ((k0l >> 3) + c) ^ (row & 7);
                    bfr[ni] = *(const short8*)((const char*)Bs + row * 256 + phys * 16);
                }
                #pragma unroll
                for (int mi = 0; mi < 4; ++mi)
                    #pragma unroll
                    for (int ni = 0; ni < 4; ++ni)
                        acc[mi][ni] = __builtin_amdgcn_mfma_f32_16x16x32_bf16(
                            af[mi], bfr[ni], acc[mi][ni], 0, 0, 0);
            }
            __syncthreads();
        }
        #pragma unroll
        for (int ni = 0; ni < 4; ++ni) {
            const int col = wn * 64 + ni * 16 + rlow;
            const float bv = bx2[col];
            #pragma unroll
            for (int q = 0; q < 4; ++q)
                #pragma unroll
                for (int mi = 0; mi < 4; ++mi) {
                    const int row = wm * 64 + mi * 16 + c * 4 + q;
                    const int byte = (row * 512 + col * 2) ^ ((row & 7) << 4);
                    *(unsigned short*)((char*)I + byte) = f2bf(fmaxf(acc[mi][ni][q] + bv, 0.f));
                }
        }
        __syncthreads();
    }

    // final stage: N=192, 2 x K=128 staging
    const __hip_bfloat16* WfT = isx ? Wx3T : Wu2T;
    f32x4 a3[4][3];
    #pragma unroll
    for (int mi = 0; mi < 4; ++mi)
        #pragma unroll
        for (int ni = 0; ni < 3; ++ni)
            a3[mi][ni] = {0.f, 0.f, 0.f, 0.f};

    for (int half = 0; half < 2; ++half) {
        const int k0b = half * 128;
        #pragma unroll
        for (int r = 0; r < 6; ++r) {
            const int i = r * 512 + tid;
            const int row = i >> 4;
            const int cl  = (i & 15) ^ (row & 7);
            __builtin_amdgcn_global_load_lds(
                GLP(WfT + (size_t)row * 256 + k0b + cl * 8),
                LDSP(Bs + i * 8), 16, 0, 0);
        }
        __syncthreads();
        #pragma unroll
        for (int k0l = 0; k0l < 128; k0l += 32) {
            short8 af[4], bfr[3];
            #pragma unroll
            for (int mi = 0; mi < 4; ++mi) {
                const int row = wm * 64 + mi * 16 + rlow;
                const int off = (row * 512 + (k0b + k0l) * 2 + c * 16) ^ ((row & 7) << 4);
                af[mi] = *(const short8*)((const char*)I + off);
            }
            #pragma unroll
            for (int ni = 0; ni < 3; ++ni) {
                const int row  = wn * 48 + ni * 16 + rlow;
                const int phys = ((k0l >> 3) + c) ^ (row & 7);
                bfr[ni] = *(const short8*)((const char*)Bs + row * 256 + phys * 16);
            }
            #pragma unroll
            for (int mi = 0; mi < 4; ++mi)
                #pragma unroll
                for (int ni = 0; ni < 3; ++ni)
                    a3[mi][ni] = __builtin_amdgcn_mfma_f32_16x16x32_bf16(
                        af[mi], bfr[ni], a3[mi][ni], 0, 0, 0);
        }
        __syncthreads();
    }
    #pragma unroll
    for (int ni = 0; ni < 3; ++ni) {
        const int col = wn * 48 + ni * 16 + rlow;
        #pragma unroll
        for (int mi = 0; mi < 4; ++mi)
            #pragma unroll
            for (int q = 0; q < 4; ++q) {
                const int row = row0 + wm * 64 + mi * 16 + c * 4 + q;
                if (isx) y[(size_t)row * 256 + 64 + col] = a3[mi][ni][q];
                else     ((unsigned short*)vout)[(size_t)row * 192 + col] = f2bf(a3[mi][ni][q]);
            }
    }
}

// ===========================================================================
// Launch D: d4g (blocks 0..2047) + stashk (2048..2559).
// ===========================================================================
__global__ __launch_bounds__(256) void d4gS(
    const __hip_bfloat16* __restrict__ u_bf, const __hip_bfloat16* __restrict__ v,
    const __hip_bfloat16* __restrict__ WBT4, const float* __restrict__ cK4,
    float* __restrict__ yp,
    const __hip_bfloat16* __restrict__ WBT, const float* __restrict__ bK,
    float* __restrict__ stash)
{
    __shared__ __align__(16) __hip_bfloat16 As[132 * 32];
    __shared__ __align__(16) __hip_bfloat16 Bs[4][128 * 32];

    const int tid  = threadIdx.x;

    if (blockIdx.x >= 2048) {
        float* uuL = (float*)As;
        const int b = blockIdx.x - 2048;
        #pragma unroll
        for (int p = 0; p < 3; ++p) {
            float val;
            if (tid < 64) val = bf2f(((const unsigned short*)u_bf)[((size_t)b * 256 + p) * 64 + tid]);
            else          val = bf2f(((const unsigned short*)v)[((size_t)b * 256 + p) * 192 + tid - 64]);
            uuL[p * 256 + tid] = val;
        }
        __syncthreads();
        const int col = tid;
        float a0 = bK[col], a1 = a0, a2 = a0;
        for (int k = 0; k < 256; ++k) {
            const float w = bf2f(((const unsigned short*)WBT)[(size_t)col * 256 + k]);
            a0 += uuL[0 * 256 + k] * w;
            a1 += uuL[1 * 256 + k] * w;
            a2 += uuL[2 * 256 + k] * w;
        }
        stash[((size_t)b * 3 + 0) * 256 + col] = a0;
        stash[((size_t)b * 3 + 1) * 256 + col] = a1;
        stash[((size_t)b * 3 + 2) * 256 + col] = a2;
        return;
    }

    const int lane = tid & 63;
    const int wid  = tid >> 6;
    const int wm   = wid & 1;
    const int wn   = wid >> 1;
    const int row0 = (blockIdx.x >> 1) * 128;
    const int col0 = (blockIdx.x & 1) * 128;
    const int rlow = lane & 15;
    const int c    = lane >> 4;

    f32x4 acc[4][4];
    #pragma unroll
    for (int mi = 0; mi < 4; ++mi)
        #pragma unroll
        for (int ni = 0; ni < 4; ++ni)
            acc[mi][ni] = {0.f, 0.f, 0.f, 0.f};

    for (int kl = 0; kl < 256; kl += 32) {
        const __hip_bfloat16* Ab; int Al, kk;
        if (kl < 64) { Ab = u_bf; Al = 64;  kk = kl; }
        else         { Ab = v;    Al = 192; kk = kl - 64; }

        #pragma unroll
        for (int r = 0; r < 3; ++r) {
            const int i = r * 256 + tid;
            if (i < 528) {
                const int row = i >> 2;
                const int cl  = (i & 3) ^ ((row >> 1) & 3);
                int srow = row0 - 4 + row;
                if (srow < 0) srow = 0;
                __builtin_amdgcn_global_load_lds(
                    GLP(Ab + (size_t)srow * Al + kk + cl * 8),
                    LDSP(As + i * 8), 16, 0, 0);
            }
        }
        #pragma unroll
        for (int r = 0; r < 8; ++r) {
            const int i = r * 256 + tid;
            const int j = i >> 9;
            const int s = i & 511;
            const int row = s >> 2;
            const int cl  = (s & 3) ^ ((row >> 1) & 3);
            __builtin_amdgcn_global_load_lds(
                GLP(WBT4 + (size_t)(col0 + row) * 1024 + j * 256 + kl + cl * 8),
                LDSP(&Bs[0][0] + i * 8), 16, 0, 0);
        }
        __syncthreads();

        #pragma unroll
        for (int j = 0; j < 4; ++j) {
            short8 bfr[4];
            #pragma unroll
            for (int ni = 0; ni < 4; ++ni) {
                const int row  = wn * 64 + ni * 16 + rlow;
                const int phys = c ^ ((row >> 1) & 3);
                bfr[ni] = *(const short8*)((const char*)Bs[j] + row * 64 + phys * 16);
            }
            #pragma unroll
            for (int mi = 0; mi < 4; ++mi) {
                const int prow = wm * 64 + mi * 16 + rlow + 3 - j;
                const int phys = c ^ ((prow >> 1) & 3);
                const short8 af = *(const short8*)((const char*)As + prow * 64 + phys * 16);
                #pragma unroll
                for (int ni = 0; ni < 4; ++ni)
                    acc[mi][ni] = __builtin_amdgcn_mfma_f32_16x16x32_bf16(
                        af, bfr[ni], acc[mi][ni], 0, 0, 0);
            }
        }
        __syncthreads();
    }

    const int q4 = lane >> 4;
    #pragma unroll
    for (int ni = 0; ni < 4; ++ni) {
        const int col = col0 + wn * 64 + ni * 16 + rlow;
        const float bv = cK4[col];
        #pragma unroll
        for (int mi = 0; mi < 4; ++mi) {
            #pragma unroll
            for (int q = 0; q < 4; ++q) {
                const int row = row0 + wm * 64 + mi * 16 + q4 * 4 + q;
                if ((row & 255) >= 4)
                    yp[(size_t)row * 256 + col] = acc[mi][ni][q] + bv;
            }
        }
    }
}

// ---------------------------------------------------------------------------
// gather hi/lo bf16 B-fragments, 16-col tile (col = col0 + rlow)
// ---------------------------------------------------------------------------
static __device__ __forceinline__ void gather_frags1(
    const float* __restrict__ M, int col0, int rlow, int kg,
    short8 (&wh)[8], short8 (&wl)[8])
{
    const int col = col0 + rlow;
    for (int kc = 0; kc < 8; ++kc) {
        const int k0 = kc * 32 + kg * 8;
        short8 h, l;
        for (int i = 0; i < 8; ++i) {
            const float w = M[(size_t)(k0 + i) * 256 + col];
            const unsigned short hb = f2bf(w);
            h[i] = (short)hb;
            l[i] = (short)f2bf(w - bf2f(hb));
        }
        wh[kc] = h;
        wl[kc] = l;
    }
}

// ---------------------------------------------------------------------------
// Launch E: unrolled scan, r17: 1024 threads / 16 waves (4 per SIMD), each
// wave owns 16 cols — same work & LDS, 2x the waves to hide the per-step
// ds_read -> MFMA -> epilogue -> barrier latency chain. 3-pass hi/lo.
// ---------------------------------------------------------------------------
__global__ __launch_bounds__(1024, 1) void scan4(
    const float* __restrict__ WK, const float* __restrict__ W4,
    const float* __restrict__ stash,
    const float* __restrict__ y, float* __restrict__ yp)
{
    __shared__ __align__(16) __hip_bfloat16 cbuf[2][2][16 * 256];

    const int tid  = threadIdx.x;
    const int lane = tid & 63;
    const int wid  = tid >> 6;          // 0..15
    const int b0   = blockIdx.x * 4;
    const int col0 = wid * 16;          // wave's 16 output cols
    const int rlow = lane & 15;
    const int kg   = lane >> 4;
    const int rswz = (rlow & 7) << 4;

    // init: phase-0 rows = y0 (4 rows x 256 cols = 1024 entries, 1/thread)
    {
        const int br = tid >> 8;
        const int cc = tid & 255;
        const float v = y[(size_t)(b0 + br) * 65536 + cc];
        yp[(size_t)(b0 + br) * 65536 + cc] = v;
        const unsigned short hb = f2bf(v);
        const unsigned short lb = f2bf(v - bf2f(hb));
        const int byte = (br * 512 + cc * 2) ^ ((br & 7) << 4);
        *(unsigned short*)((char*)&cbuf[0][0][0] + byte) = hb;
        *(unsigned short*)((char*)&cbuf[0][1][0] + byte) = lb;
    }
    __syncthreads();

    short8 wh[8], wl[8];
    gather_frags1(WK, col0, rlow, kg, wh, wl);

    // prologue p = 1..3
    for (int p = 1; p < 4; ++p) {
        f32x4 aHH = {0.f,0.f,0.f,0.f}, aHL = {0.f,0.f,0.f,0.f}, aLH = {0.f,0.f,0.f,0.f};
        const char* hbase = (const char*)&cbuf[0][0][0];
        const char* lbase = (const char*)&cbuf[0][1][0];
        #pragma unroll
        for (int kc = 0; kc < 8; ++kc) {
            const int off = (rlow * 512 + kg * 16 + kc * 64) ^ rswz;
            const short8 ah = *(const short8*)(hbase + off);
            const short8 al = *(const short8*)(lbase + off);
            aHH = __builtin_amdgcn_mfma_f32_16x16x32_bf16(ah, wh[kc], aHH, 0, 0, 0);
            aHL = __builtin_amdgcn_mfma_f32_16x16x32_bf16(ah, wl[kc], aHL, 0, 0, 0);
            aLH = __builtin_amdgcn_mfma_f32_16x16x32_bf16(al, wh[kc], aLH, 0, 0, 0);
        }
        __builtin_amdgcn_sched_barrier(0);
        asm volatile("s_waitcnt lgkmcnt(0)" ::: "memory");
        __builtin_amdgcn_s_barrier();
        __builtin_amdgcn_sched_barrier(0);

        if (kg == p - 1) {
            const int col = col0 + rlow;
            #pragma unroll
            for (int q = 0; q < 4; ++q) {
                const float cv = stash[((size_t)(b0 + q) * 3 + (p - 1)) * 256 + col];
                const float yv = aHH[q] + aHL[q] + aLH[q] + cv;
                const int wr = p * 4 + q;
                const unsigned short hb = f2bf(yv);
                const unsigned short lb = f2bf(yv - bf2f(hb));
                const int byte = (wr * 512 + col * 2) ^ ((wr & 7) << 4);
                *(unsigned short*)((char*)&cbuf[0][0][0] + byte) = hb;
                *(unsigned short*)((char*)&cbuf[0][1][0] + byte) = lb;
                yp[(size_t)(b0 + q) * 65536 + (size_t)p * 256 + col] = yv;
            }
        }
        __builtin_amdgcn_sched_barrier(0);
        asm volatile("s_waitcnt lgkmcnt(0)" ::: "memory");
        __builtin_amdgcn_s_barrier();
        __builtin_amdgcn_sched_barrier(0);
    }

    gather_frags1(W4, col0, rlow, kg, wh, wl);

    // prefetch D4 for s=0
    float dv[4];
    {
        const int col = col0 + rlow;
        #pragma unroll
        for (int q = 0; q < 4; ++q)
            dv[q] = yp[(size_t)(b0 + q) * 65536 + (size_t)(4 + kg) * 256 + col];
    }

    int cur = 0;
    for (int s = 0; s < 63; ++s) {
        const int tb = 4 + s * 4;

        float dn[4];
        if (s < 62) {
            const int col = col0 + rlow;
            #pragma unroll
            for (int q = 0; q < 4; ++q)
                dn[q] = yp[(size_t)(b0 + q) * 65536
                           + (size_t)(tb + 4 + kg) * 256 + col];
        }

        f32x4 aHH = {0.f,0.f,0.f,0.f}, aHL = {0.f,0.f,0.f,0.f}, aLH = {0.f,0.f,0.f,0.f};
        const char* hbase = (const char*)&cbuf[cur][0][0];
        const char* lbase = (const char*)&cbuf[cur][1][0];
        #pragma unroll
        for (int kc = 0; kc < 8; ++kc) {
            const int off = (rlow * 512 + kg * 16 + kc * 64) ^ rswz;
            const short8 ah = *(const short8*)(hbase + off);
            const short8 al = *(const short8*)(lbase + off);
            aHH = __builtin_amdgcn_mfma_f32_16x16x32_bf16(ah, wh[kc], aHH, 0, 0, 0);
            aHL = __builtin_amdgcn_mfma_f32_16x16x32_bf16(ah, wl[kc], aHL, 0, 0, 0);
            aLH = __builtin_amdgcn_mfma_f32_16x16x32_bf16(al, wh[kc], aLH, 0, 0, 0);
        }

        char* whb = (char*)&cbuf[cur ^ 1][0][0];
        char* wlb = (char*)&cbuf[cur ^ 1][1][0];
        {
            const int col = col0 + rlow;
            #pragma unroll
            for (int q = 0; q < 4; ++q) {
                const int row = kg * 4 + q;
                const float yv = aHH[q] + aHL[q] + aLH[q] + dv[q];
                const unsigned short hb = f2bf(yv);
                const unsigned short lb = f2bf(yv - bf2f(hb));
                const int byte = (row * 512 + col * 2) ^ ((row & 7) << 4);
                *(unsigned short*)(whb + byte) = hb;
                *(unsigned short*)(wlb + byte) = lb;
                yp[(size_t)(b0 + q) * 65536 + (size_t)(tb + kg) * 256 + col] = yv;
            }
        }
        if (s < 62) {
            #pragma unroll
            for (int q = 0; q < 4; ++q)
                dv[q] = dn[q];
        }

        __builtin_amdgcn_sched_barrier(0);
        asm volatile("s_waitcnt lgkmcnt(0)" ::: "memory");
        __builtin_amdgcn_s_barrier();
        __builtin_amdgcn_sched_barrier(0);
        cur ^= 1;
    }
}

// ---------------------------------------------------------------------------
extern "C" void kernel_launch(void* const* d_in, const int* in_sizes, int n_in,
                              void* d_out, int out_size, void* d_ws, size_t ws_size,
                              hipStream_t stream)
{
    const float* x   = (const float*)d_in[0];
    const float* u   = (const float*)d_in[1];
    const float* Wx1 = (const float*)d_in[2];
    const float* bx1 = (const float*)d_in[3];
    const float* Wx2 = (const float*)d_in[4];
    const float* bx2 = (const float*)d_in[5];
    const float* Wx3 = (const float*)d_in[6];
    const float* Wu1 = (const float*)d_in[7];
    const float* bu1 = (const float*)d_in[8];
    const float* Wu2 = (const float*)d_in[9];
    const float* WB  = (const float*)d_in[10];
    const float* WK  = (const float*)d_in[11];
    const float* bK  = (const float*)d_in[12];

    float* y  = (float*)d_out;
    float* yp = y + (size_t)MM * 256;

    char* ws = (char*)d_ws;
    __hip_bfloat16* x_bf = (__hip_bfloat16*)(ws);
    __hip_bfloat16* u_bf = (__hip_bfloat16*)(ws + 16777216);
    __hip_bfloat16* wTb  = (__hip_bfloat16*)(ws + 33554432);
    __hip_bfloat16* Wx1T = wTb;
    __hip_bfloat16* Wx2T = wTb + 16384;
    __hip_bfloat16* Wx3T = wTb + 81920;
    __hip_bfloat16* Wu1T = wTb + 131072;
    __hip_bfloat16* Wu2T = wTb + 147456;
    __hip_bfloat16* WBT  = wTb + 196608;
    __hip_bfloat16* t2   = (__hip_bfloat16*)(ws + 34078720);     // v (M x 192)
    float* W2f   = (float*)(ws + 101187584);
    float* W3f   = (float*)(ws + 101449728);
    float* W4f   = (float*)(ws + 101711872);
    float* WBWf  = (float*)(ws + 101974016);
    float* WBW2f = (float*)(ws + 102236160);
    float* WBW3f = (float*)(ws + 102498304);
    __hip_bfloat16* WBT4 = (__hip_bfloat16*)(ws + 102760448);
    float* cK4   = (float*)(ws + 103284736);
    float* stash = (float*)(ws + 103285760);

    prepA<<<17440, dim3(256), 0, stream>>>(x, u, x_bf, u_bf, y,
        Wx1, Wx2, Wx3, Wu1, Wu2, WB,
        Wx1T, Wx2T, Wx3T, Wu1T, Wu2T, WBT,
        WK, WB, W2f, WBWf);

    {
        G5 L2 = {{W2f, W2f, WBWf, WBWf, nullptr},
                 {WK, W2f, WK, W2f, nullptr},
                 {W3f, W4f, WBW2f, WBW3f, nullptr}};
        wgemm<<<64, dim3(256), 0, stream>>>(L2);
    }

    ffC<<<2561, dim3(512), 0, stream>>>(x_bf, u_bf,
        Wx1T, bx1, Wx2T, bx2, Wx3T, Wu1T, bu1, Wu2T,
        y, t2,
        WB, WBWf, WBW2f, WBW3f, WBT4,
        bK, WK, W2f, W3f, cK4);

    d4gS<<<2560, dim3(256), 0, stream>>>(u_bf, t2, WBT4, cK4, yp, WBT, bK, stash);

    scan4<<<128, dim3(1024), 0, stream>>>(WK, W4f, stash, y, yp);
}

// Round 18
// 391.552 us; speedup vs baseline: 1.0579x; 1.0278x over previous
//
#include <hip/hip_runtime.h>
#include <hip/hip_bf16.h>

#define MM 131072

typedef __attribute__((ext_vector_type(8))) short short8;
typedef __attribute__((ext_vector_type(4))) float f32x4;

#define GLP(p) (const __attribute__((address_space(1))) void*)(p)
#define LDSP(p) (__attribute__((address_space(3))) void*)(p)

typedef __attribute__((address_space(1))) float gfloat;

static __device__ __forceinline__ unsigned short f2bf(float f) {
    union { float f; unsigned int u; } v; v.f = f;
    unsigned int r = v.u + 0x7FFF + ((v.u >> 16) & 1);  // RNE
    return (unsigned short)(r >> 16);
}
static __device__ __forceinline__ float bf2f(unsigned short h) {
    union { float f; unsigned int u; } v; v.u = ((unsigned int)h) << 16;
    return v.f;
}

// ===========================================================================
// Launch A: prep (conv x/u -> bf16, x->y cols 0..63, 6x W->WT) + wgemm L1
// ===========================================================================
__global__ __launch_bounds__(256) void prepA(
    const float* __restrict__ x, const float* __restrict__ u,
    __hip_bfloat16* __restrict__ xb, __hip_bfloat16* __restrict__ ub,
    float* __restrict__ y,
    const float* __restrict__ W0, const float* __restrict__ W1,
    const float* __restrict__ W2, const float* __restrict__ W3,
    const float* __restrict__ W4, const float* __restrict__ W5,
    __hip_bfloat16* __restrict__ T0, __hip_bfloat16* __restrict__ T1,
    __hip_bfloat16* __restrict__ T2, __hip_bfloat16* __restrict__ T3,
    __hip_bfloat16* __restrict__ T4, __hip_bfloat16* __restrict__ T5,
    const float* __restrict__ WK, const float* __restrict__ WB,
    float* __restrict__ W2f, float* __restrict__ WBWf)
{
    __shared__ __align__(16) float As[16][68];
    __shared__ __align__(16) float Ws[16][64];

    if (blockIdx.x < 16384) {
        int i = blockIdx.x * 256 + threadIdx.x;
        const float* s; __hip_bfloat16* d; int j; bool isx;
        if (i < 2097152) { s = x; d = xb; j = i; isx = true; }
        else             { s = u; d = ub; j = i - 2097152; isx = false; }
        const float4 v = ((const float4*)s)[j];
        union { unsigned short h[4]; uint2 u2; } p;
        p.h[0] = f2bf(v.x); p.h[1] = f2bf(v.y);
        p.h[2] = f2bf(v.z); p.h[3] = f2bf(v.w);
        ((uint2*)d)[j] = p.u2;
        if (isx) {
            const int r = j >> 4, q = j & 15;
            ((float4*)(y + (size_t)r * 256))[q] = v;
        }
    } else if (blockIdx.x < 17408) {
        const int b = blockIdx.x - 16384;
        const float* W; __hip_bfloat16* T; int K, N, i0;
        if      (b < 64)  { W = W0; T = T0; K = 64;  N = 256; i0 = b; }
        else if (b < 320) { W = W1; T = T1; K = 256; N = 256; i0 = b - 64; }
        else if (b < 512) { W = W2; T = T2; K = 256; N = 192; i0 = b - 320; }
        else if (b < 576) { W = W3; T = T3; K = 64;  N = 256; i0 = b - 512; }
        else if (b < 768) { W = W4; T = T4; K = 256; N = 192; i0 = b - 576; }
        else              { W = W5; T = T5; K = 256; N = 256; i0 = b - 768; }
        const int i = i0 * 256 + threadIdx.x;
        if (i < K * N) {
            const int n = i / K, k = i - n * K;
            T[i] = __float2bfloat16(W[(size_t)k * N + n]);
        }
    } else {
        const int tile = blockIdx.x - 17408;
        const int e  = tile >> 4;
        const int tl = tile & 15;
        const float* A = e ? WB : WK;
        const float* W = WK;
        float*       C = e ? WBWf : W2f;
        const int row0 = (tl >> 2) * 64;
        const int col0 = (tl & 3) * 64;
        const int tx = threadIdx.x & 15;
        const int ty = threadIdx.x >> 4;
        float acc[4][4] = {};
        for (int k0 = 0; k0 < 256; k0 += 16) {
            {
                const int kk = threadIdx.x & 15;
                const int r  = threadIdx.x >> 4;
                #pragma unroll
                for (int rr = 0; rr < 4; ++rr)
                    As[kk][r + rr * 16] = A[(size_t)(row0 + r + rr * 16) * 256 + k0 + kk];
            }
            {
                const int n  = threadIdx.x & 63;
                const int kz = threadIdx.x >> 6;
                #pragma unroll
                for (int kq = 0; kq < 4; ++kq) {
                    const int kk = kz + kq * 4;
                    Ws[kk][n] = W[(size_t)(k0 + kk) * 256 + col0 + n];
                }
            }
            __syncthreads();
            #pragma unroll
            for (int kk = 0; kk < 16; ++kk) {
                const float4 a4 = *(const float4*)&As[kk][ty * 4];
                const float4 w4 = *(const float4*)&Ws[kk][tx * 4];
                const float av[4] = {a4.x, a4.y, a4.z, a4.w};
                const float wv[4] = {w4.x, w4.y, w4.z, w4.w};
                #pragma unroll
                for (int i = 0; i < 4; ++i)
                    #pragma unroll
                    for (int j = 0; j < 4; ++j)
                        acc[i][j] += av[i] * wv[j];
            }
            __syncthreads();
        }
        #pragma unroll
        for (int i = 0; i < 4; ++i)
            #pragma unroll
            for (int j = 0; j < 4; ++j)
                C[(size_t)(row0 + ty * 4 + i) * 256 + col0 + tx * 4 + j] = acc[i][j];
    }
}

// ===========================================================================
// Launch B: wgemm L2 (4 GEMMs: W3, W4, WBW2, WBW3)
// ===========================================================================
struct G5 { const float* a[5]; const float* b[5]; float* c[5]; };

__global__ __launch_bounds__(256) void wgemm(G5 P)
{
    __shared__ __align__(16) float As[16][68];
    __shared__ __align__(16) float Ws[16][64];

    const int e  = blockIdx.x >> 4;
    const int tl = blockIdx.x & 15;
    const float* A = P.a[e];
    const float* W = P.b[e];
    float*       C = P.c[e];
    const int row0 = (tl >> 2) * 64;
    const int col0 = (tl & 3) * 64;

    const int tx = threadIdx.x & 15;
    const int ty = threadIdx.x >> 4;

    float acc[4][4] = {};

    for (int k0 = 0; k0 < 256; k0 += 16) {
        {
            const int kk = threadIdx.x & 15;
            const int r  = threadIdx.x >> 4;
            #pragma unroll
            for (int rr = 0; rr < 4; ++rr)
                As[kk][r + rr * 16] = A[(size_t)(row0 + r + rr * 16) * 256 + k0 + kk];
        }
        {
            const int n  = threadIdx.x & 63;
            const int kz = threadIdx.x >> 6;
            #pragma unroll
            for (int kq = 0; kq < 4; ++kq) {
                const int kk = kz + kq * 4;
                Ws[kk][n] = W[(size_t)(k0 + kk) * 256 + col0 + n];
            }
        }
        __syncthreads();
        #pragma unroll
        for (int kk = 0; kk < 16; ++kk) {
            const float4 a4 = *(const float4*)&As[kk][ty * 4];
            const float4 w4 = *(const float4*)&Ws[kk][tx * 4];
            const float av[4] = {a4.x, a4.y, a4.z, a4.w};
            const float wv[4] = {w4.x, w4.y, w4.z, w4.w};
            #pragma unroll
            for (int i = 0; i < 4; ++i)
                #pragma unroll
                for (int j = 0; j < 4; ++j)
                    acc[i][j] += av[i] * wv[j];
        }
        __syncthreads();
    }

    #pragma unroll
    for (int i = 0; i < 4; ++i)
        #pragma unroll
        for (int j = 0; j < 4; ++j)
            C[(size_t)(row0 + ty * 4 + i) * 256 + col0 + tx * 4 + j] = acc[i][j];
}

// ===========================================================================
// Launch C (r15-measured-good): ffx (0..1023) + ffu (1024..2047) +
// bigbt (2048..2559) + cK4 (2560). 512 threads.
// ===========================================================================
__global__ __launch_bounds__(512) void ffC(
    const __hip_bfloat16* __restrict__ x_bf,
    const __hip_bfloat16* __restrict__ u_bf,
    const __hip_bfloat16* __restrict__ Wx1T, const float* __restrict__ bx1,
    const __hip_bfloat16* __restrict__ Wx2T, const float* __restrict__ bx2,
    const __hip_bfloat16* __restrict__ Wx3T,
    const __hip_bfloat16* __restrict__ Wu1T, const float* __restrict__ bu1,
    const __hip_bfloat16* __restrict__ Wu2T,
    float* __restrict__ y, __hip_bfloat16* __restrict__ vout,
    const float* __restrict__ WB, const float* __restrict__ WBW,
    const float* __restrict__ WBW2, const float* __restrict__ WBW3,
    __hip_bfloat16* __restrict__ T4,
    const float* __restrict__ bK, const float* __restrict__ WK,
    const float* __restrict__ W2f, const float* __restrict__ W3f,
    float* __restrict__ cK4)
{
    __shared__ __align__(16) __hip_bfloat16 I[128 * 256];    // 64 KB
    __shared__ __align__(16) __hip_bfloat16 Bs[256 * 128];   // 64 KB
    __shared__ __align__(16) __hip_bfloat16 As[128 * 64];    // 16 KB

    const int tid  = threadIdx.x;

    if (blockIdx.x >= 2048) {
        if (blockIdx.x < 2560) {
            const int o = (blockIdx.x - 2048) * 512 + tid;
            const int n = o >> 10;
            const int rem = o & 1023;
            const int j = rem >> 8, k = rem & 255;
            const float* src = (j == 0) ? WB : (j == 1) ? WBW : (j == 2) ? WBW2 : WBW3;
            ((unsigned short*)T4)[o] = f2bf(src[(size_t)k * 256 + n]);
        } else {
            if (tid < 256) {
                const int col = tid;
                float s = bK[col];
                for (int k = 0; k < 256; ++k)
                    s += bK[k] * (WK[(size_t)k * 256 + col] + W2f[(size_t)k * 256 + col]
                                  + W3f[(size_t)k * 256 + col]);
                cK4[col] = s;
            }
        }
        return;
    }

    const bool isx = blockIdx.x < 1024;
    const __hip_bfloat16* in  = isx ? x_bf : u_bf;
    const __hip_bfloat16* W1T = isx ? Wx1T : Wu1T;
    const float*          b1  = isx ? bx1  : bu1;
    const int lane = tid & 63;
    const int wid  = tid >> 6;
    const int wm   = wid & 1;
    const int wn   = wid >> 1;
    const int row0 = (blockIdx.x & 1023) * 128;
    const int rlow = lane & 15;
    const int c    = lane >> 4;

    f32x4 acc[4][4];
    #pragma unroll
    for (int mi = 0; mi < 4; ++mi)
        #pragma unroll
        for (int ni = 0; ni < 4; ++ni)
            acc[mi][ni] = {0.f, 0.f, 0.f, 0.f};

    // stage 1: K=64 fully staged, 1 barrier pair
    {
        #pragma unroll
        for (int r = 0; r < 2; ++r) {
            const int i = r * 512 + tid;
            const int row = i >> 3;
            const int cl  = (i & 7) ^ (row & 7);
            __builtin_amdgcn_global_load_lds(
                GLP(in + (size_t)(row0 + row) * 64 + cl * 8),
                LDSP(As + i * 8), 16, 0, 0);
        }
        #pragma unroll
        for (int r = 0; r < 4; ++r) {
            const int i = r * 512 + tid;
            const int row = i >> 3;
            const int cl  = (i & 7) ^ (row & 7);
            __builtin_amdgcn_global_load_lds(
                GLP(W1T + (size_t)row * 64 + cl * 8),
                LDSP(Bs + i * 8), 16, 0, 0);
        }
        __syncthreads();
        #pragma unroll
        for (int k0 = 0; k0 < 64; k0 += 32) {
            short8 af[4], bfr[4];
            #pragma unroll
            for (int mi = 0; mi < 4; ++mi) {
                const int row  = wm * 64 + mi * 16 + rlow;
                const int phys = ((k0 >> 3) + c) ^ (row & 7);
                af[mi] = *(const short8*)((const char*)As + row * 128 + phys * 16);
            }
            #pragma unroll
            for (int ni = 0; ni < 4; ++ni) {
                const int row  = wn * 64 + ni * 16 + rlow;
                const int phys = ((k0 >> 3) + c) ^ (row & 7);
                bfr[ni] = *(const short8*)((const char*)Bs + row * 128 + phys * 16);
            }
            #pragma unroll
            for (int mi = 0; mi < 4; ++mi)
                #pragma unroll
                for (int ni = 0; ni < 4; ++ni)
                    acc[mi][ni] = __builtin_amdgcn_mfma_f32_16x16x32_bf16(
                        af[mi], bfr[ni], acc[mi][ni], 0, 0, 0);
        }
        __syncthreads();
        #pragma unroll
        for (int ni = 0; ni < 4; ++ni) {
            const int col = wn * 64 + ni * 16 + rlow;
            const float bv = b1[col];
            #pragma unroll
            for (int q = 0; q < 4; ++q)
                #pragma unroll
                for (int mi = 0; mi < 4; ++mi) {
                    const int row = wm * 64 + mi * 16 + c * 4 + q;
                    const int byte = (row * 512 + col * 2) ^ ((row & 7) << 4);
                    *(unsigned short*)((char*)I + byte) = f2bf(fmaxf(acc[mi][ni][q] + bv, 0.f));
                }
        }
        __syncthreads();
    }

    if (isx) {
        // stage 2: 2 x K=128 staging
        #pragma unroll
        for (int mi = 0; mi < 4; ++mi)
            #pragma unroll
            for (int ni = 0; ni < 4; ++ni)
                acc[mi][ni] = {0.f, 0.f, 0.f, 0.f};

        for (int half = 0; half < 2; ++half) {
            const int k0b = half * 128;
            #pragma unroll
            for (int r = 0; r < 8; ++r) {
                const int i = r * 512 + tid;
                const int row = i >> 4;
                const int cl  = (i & 15) ^ (row & 7);
                __builtin_amdgcn_global_load_lds(
                    GLP(Wx2T + (size_t)row * 256 + k0b + cl * 8),
                    LDSP(Bs + i * 8), 16, 0, 0);
            }
            __syncthreads();
            #pragma unroll
            for (int k0l = 0; k0l < 128; k0l += 32) {
                short8 af[4], bfr[4];
                #pragma unroll
                for (int mi = 0; mi < 4; ++mi) {
                    const int row = wm * 64 + mi * 16 + rlow;
                    const int off = (row * 512 + (k0b + k0l) * 2 + c * 16) ^ ((row & 7) << 4);
                    af[mi] = *(const short8*)((const char*)I + off);
                }
                #pragma unroll
                for (int ni = 0; ni < 4; ++ni) {
                    const int row  = wn * 64 + ni * 16 + rlow;
                    const int phys = ((k0l >> 3) + c) ^ (row & 7);
                    bfr[ni] = *(const short8*)((const char*)Bs + row * 256 + phys * 16);
                }
                #pragma unroll
                for (int mi = 0; mi < 4; ++mi)
                    #pragma unroll
                    for (int ni = 0; ni < 4; ++ni)
                        acc[mi][ni] = __builtin_amdgcn_mfma_f32_16x16x32_bf16(
                            af[mi], bfr[ni], acc[mi][ni], 0, 0, 0);
            }
            __syncthreads();
        }
        #pragma unroll
        for (int ni = 0; ni < 4; ++ni) {
            const int col = wn * 64 + ni * 16 + rlow;
            const float bv = bx2[col];
            #pragma unroll
            for (int q = 0; q < 4; ++q)
                #pragma unroll
                for (int mi = 0; mi < 4; ++mi) {
                    const int row = wm * 64 + mi * 16 + c * 4 + q;
                    const int byte = (row * 512 + col * 2) ^ ((row & 7) << 4);
                    *(unsigned short*)((char*)I + byte) = f2bf(fmaxf(acc[mi][ni][q] + bv, 0.f));
                }
        }
        __syncthreads();
    }

    // final stage: N=192, 2 x K=128 staging
    const __hip_bfloat16* WfT = isx ? Wx3T : Wu2T;
    f32x4 a3[4][3];
    #pragma unroll
    for (int mi = 0; mi < 4; ++mi)
        #pragma unroll
        for (int ni = 0; ni < 3; ++ni)
            a3[mi][ni] = {0.f, 0.f, 0.f, 0.f};

    for (int half = 0; half < 2; ++half) {
        const int k0b = half * 128;
        #pragma unroll
        for (int r = 0; r < 6; ++r) {
            const int i = r * 512 + tid;
            const int row = i >> 4;
            const int cl  = (i & 15) ^ (row & 7);
            __builtin_amdgcn_global_load_lds(
                GLP(WfT + (size_t)row * 256 + k0b + cl * 8),
                LDSP(Bs + i * 8), 16, 0, 0);
        }
        __syncthreads();
        #pragma unroll
        for (int k0l = 0; k0l < 128; k0l += 32) {
            short8 af[4], bfr[3];
            #pragma unroll
            for (int mi = 0; mi < 4; ++mi) {
                const int row = wm * 64 + mi * 16 + rlow;
                const int off = (row * 512 + (k0b + k0l) * 2 + c * 16) ^ ((row & 7) << 4);
                af[mi] = *(const short8*)((const char*)I + off);
            }
            #pragma unroll
            for (int ni = 0; ni < 3; ++ni) {
                const int row  = wn * 48 + ni * 16 + rlow;
                const int phys = ((k0l >> 3) + c) ^ (row & 7);
                bfr[ni] = *(const short8*)((const char*)Bs + row * 256 + phys * 16);
            }
            #pragma unroll
            for (int mi = 0; mi < 4; ++mi)
                #pragma unroll
                for (int ni = 0; ni < 3; ++ni)
                    a3[mi][ni] = __builtin_amdgcn_mfma_f32_16x16x32_bf16(
                        af[mi], bfr[ni], a3[mi][ni], 0, 0, 0);
        }
        __syncthreads();
    }
    #pragma unroll
    for (int ni = 0; ni < 3; ++ni) {
        const int col = wn * 48 + ni * 16 + rlow;
        #pragma unroll
        for (int mi = 0; mi < 4; ++mi)
            #pragma unroll
            for (int q = 0; q < 4; ++q) {
                const int row = row0 + wm * 64 + mi * 16 + c * 4 + q;
                if (isx) y[(size_t)row * 256 + 64 + col] = a3[mi][ni][q];
                else     ((unsigned short*)vout)[(size_t)row * 192 + col] = f2bf(a3[mi][ni][q]);
            }
    }
}

// ===========================================================================
// Launch D: d4g (blocks 0..2047) + stashk (2048..2559).
// ===========================================================================
__global__ __launch_bounds__(256) void d4gS(
    const __hip_bfloat16* __restrict__ u_bf, const __hip_bfloat16* __restrict__ v,
    const __hip_bfloat16* __restrict__ WBT4, const float* __restrict__ cK4,
    float* __restrict__ yp,
    const __hip_bfloat16* __restrict__ WBT, const float* __restrict__ bK,
    float* __restrict__ stash)
{
    __shared__ __align__(16) __hip_bfloat16 As[132 * 32];
    __shared__ __align__(16) __hip_bfloat16 Bs[4][128 * 32];

    const int tid  = threadIdx.x;

    if (blockIdx.x >= 2048) {
        float* uuL = (float*)As;
        const int b = blockIdx.x - 2048;
        #pragma unroll
        for (int p = 0; p < 3; ++p) {
            float val;
            if (tid < 64) val = bf2f(((const unsigned short*)u_bf)[((size_t)b * 256 + p) * 64 + tid]);
            else          val = bf2f(((const unsigned short*)v)[((size_t)b * 256 + p) * 192 + tid - 64]);
            uuL[p * 256 + tid] = val;
        }
        __syncthreads();
        const int col = tid;
        float a0 = bK[col], a1 = a0, a2 = a0;
        for (int k = 0; k < 256; ++k) {
            const float w = bf2f(((const unsigned short*)WBT)[(size_t)col * 256 + k]);
            a0 += uuL[0 * 256 + k] * w;
            a1 += uuL[1 * 256 + k] * w;
            a2 += uuL[2 * 256 + k] * w;
        }
        stash[((size_t)b * 3 + 0) * 256 + col] = a0;
        stash[((size_t)b * 3 + 1) * 256 + col] = a1;
        stash[((size_t)b * 3 + 2) * 256 + col] = a2;
        return;
    }

    const int lane = tid & 63;
    const int wid  = tid >> 6;
    const int wm   = wid & 1;
    const int wn   = wid >> 1;
    const int row0 = (blockIdx.x >> 1) * 128;
    const int col0 = (blockIdx.x & 1) * 128;
    const int rlow = lane & 15;
    const int c    = lane >> 4;

    f32x4 acc[4][4];
    #pragma unroll
    for (int mi = 0; mi < 4; ++mi)
        #pragma unroll
        for (int ni = 0; ni < 4; ++ni)
            acc[mi][ni] = {0.f, 0.f, 0.f, 0.f};

    for (int kl = 0; kl < 256; kl += 32) {
        const __hip_bfloat16* Ab; int Al, kk;
        if (kl < 64) { Ab = u_bf; Al = 64;  kk = kl; }
        else         { Ab = v;    Al = 192; kk = kl - 64; }

        #pragma unroll
        for (int r = 0; r < 3; ++r) {
            const int i = r * 256 + tid;
            if (i < 528) {
                const int row = i >> 2;
                const int cl  = (i & 3) ^ ((row >> 1) & 3);
                int srow = row0 - 4 + row;
                if (srow < 0) srow = 0;
                __builtin_amdgcn_global_load_lds(
                    GLP(Ab + (size_t)srow * Al + kk + cl * 8),
                    LDSP(As + i * 8), 16, 0, 0);
            }
        }
        #pragma unroll
        for (int r = 0; r < 8; ++r) {
            const int i = r * 256 + tid;
            const int j = i >> 9;
            const int s = i & 511;
            const int row = s >> 2;
            const int cl  = (s & 3) ^ ((row >> 1) & 3);
            __builtin_amdgcn_global_load_lds(
                GLP(WBT4 + (size_t)(col0 + row) * 1024 + j * 256 + kl + cl * 8),
                LDSP(&Bs[0][0] + i * 8), 16, 0, 0);
        }
        __syncthreads();

        #pragma unroll
        for (int j = 0; j < 4; ++j) {
            short8 bfr[4];
            #pragma unroll
            for (int ni = 0; ni < 4; ++ni) {
                const int row  = wn * 64 + ni * 16 + rlow;
                const int phys = c ^ ((row >> 1) & 3);
                bfr[ni] = *(const short8*)((const char*)Bs[j] + row * 64 + phys * 16);
            }
            #pragma unroll
            for (int mi = 0; mi < 4; ++mi) {
                const int prow = wm * 64 + mi * 16 + rlow + 3 - j;
                const int phys = c ^ ((prow >> 1) & 3);
                const short8 af = *(const short8*)((const char*)As + prow * 64 + phys * 16);
                #pragma unroll
                for (int ni = 0; ni < 4; ++ni)
                    acc[mi][ni] = __builtin_amdgcn_mfma_f32_16x16x32_bf16(
                        af, bfr[ni], acc[mi][ni], 0, 0, 0);
            }
        }
        __syncthreads();
    }

    const int q4 = lane >> 4;
    #pragma unroll
    for (int ni = 0; ni < 4; ++ni) {
        const int col = col0 + wn * 64 + ni * 16 + rlow;
        const float bv = cK4[col];
        #pragma unroll
        for (int mi = 0; mi < 4; ++mi) {
            #pragma unroll
            for (int q = 0; q < 4; ++q) {
                const int row = row0 + wm * 64 + mi * 16 + q4 * 4 + q;
                if ((row & 255) >= 4)
                    yp[(size_t)row * 256 + col] = acc[mi][ni][q] + bv;
            }
        }
    }
}

// ---------------------------------------------------------------------------
// gather hi/lo bf16 B-fragments of a 256x256 fp32 matrix
// ---------------------------------------------------------------------------
static __device__ __forceinline__ void gather_frags(
    const float* __restrict__ M, int col0, int rlow, int kg,
    short8 (&wh)[2][8], short8 (&wl)[2][8])
{
    #pragma unroll
    for (int tile = 0; tile < 2; ++tile) {
        const int col = col0 + tile * 16 + rlow;
        for (int kc = 0; kc < 8; ++kc) {
            const int k0 = kc * 32 + kg * 8;
            short8 h, l;
            for (int i = 0; i < 8; ++i) {
                const float w = M[(size_t)(k0 + i) * 256 + col];
                const unsigned short hb = f2bf(w);
                h[i] = (short)hb;
                l[i] = (short)f2bf(w - bf2f(hb));
            }
            wh[tile][kc] = h;
            wl[tile][kc] = l;
        }
    }
}

// ---------------------------------------------------------------------------
// Launch E: unrolled scan (r15 body), r18: ALL global accesses (y, yp, stash)
// via explicit address_space(1) pointers — forces global_load/global_store
// (vmcnt-only) so the per-step `s_waitcnt lgkmcnt(0)` really covers LDS only.
// If the compiler was emitting flat_* (lgkm-counted), this removes an HBM
// round-trip from every serial step.
// ---------------------------------------------------------------------------
__global__ __launch_bounds__(512, 1) void scan4(
    const float* __restrict__ WK, const float* __restrict__ W4,
    const float* __restrict__ stash,
    const float* __restrict__ y, float* __restrict__ yp)
{
    __shared__ __align__(16) __hip_bfloat16 cbuf[2][2][16 * 256];

    const gfloat* __restrict__ gy  = (const gfloat*)y;
    gfloat* __restrict__ gyp       = (gfloat*)yp;
    const gfloat* __restrict__ gst = (const gfloat*)stash;

    const int tid  = threadIdx.x;
    const int lane = tid & 63;
    const int wid  = tid >> 6;
    const int b0   = blockIdx.x * 4;
    const int col0 = wid * 32;
    const int rlow = lane & 15;
    const int kg   = lane >> 4;
    const int rswz = (rlow & 7) << 4;

    #pragma unroll
    for (int e = 0; e < 2; ++e) {
        const int idx = tid * 2 + e;
        const int br  = idx >> 8;
        const int cc  = idx & 255;
        const float v = gy[(size_t)(b0 + br) * 65536 + cc];
        gyp[(size_t)(b0 + br) * 65536 + cc] = v;
        const unsigned short hb = f2bf(v);
        const unsigned short lb = f2bf(v - bf2f(hb));
        const int byte = (br * 512 + cc * 2) ^ ((br & 7) << 4);
        *(unsigned short*)((char*)&cbuf[0][0][0] + byte) = hb;
        *(unsigned short*)((char*)&cbuf[0][1][0] + byte) = lb;
    }
    __syncthreads();

    short8 wh[2][8], wl[2][8];
    gather_frags(WK, col0, rlow, kg, wh, wl);

    for (int p = 1; p < 4; ++p) {
        f32x4 aHH[2], aHL[2], aLH[2], bHH[2], bHL[2], bLH[2];
        #pragma unroll
        for (int tile = 0; tile < 2; ++tile) {
            aHH[tile] = {0.f,0.f,0.f,0.f}; aHL[tile] = {0.f,0.f,0.f,0.f}; aLH[tile] = {0.f,0.f,0.f,0.f};
            bHH[tile] = {0.f,0.f,0.f,0.f}; bHL[tile] = {0.f,0.f,0.f,0.f}; bLH[tile] = {0.f,0.f,0.f,0.f};
        }
        const char* hbase = (const char*)&cbuf[0][0][0];
        const char* lbase = (const char*)&cbuf[0][1][0];
        #pragma unroll
        for (int kc = 0; kc < 4; ++kc) {
            const int off = (rlow * 512 + kg * 16 + kc * 64) ^ rswz;
            const short8 ah = *(const short8*)(hbase + off);
            const short8 al = *(const short8*)(lbase + off);
            aHH[0] = __builtin_amdgcn_mfma_f32_16x16x32_bf16(ah, wh[0][kc], aHH[0], 0, 0, 0);
            aHH[1] = __builtin_amdgcn_mfma_f32_16x16x32_bf16(ah, wh[1][kc], aHH[1], 0, 0, 0);
            aHL[0] = __builtin_amdgcn_mfma_f32_16x16x32_bf16(ah, wl[0][kc], aHL[0], 0, 0, 0);
            aHL[1] = __builtin_amdgcn_mfma_f32_16x16x32_bf16(ah, wl[1][kc], aHL[1], 0, 0, 0);
            aLH[0] = __builtin_amdgcn_mfma_f32_16x16x32_bf16(al, wh[0][kc], aLH[0], 0, 0, 0);
            aLH[1] = __builtin_amdgcn_mfma_f32_16x16x32_bf16(al, wh[1][kc], aLH[1], 0, 0, 0);
        }
        #pragma unroll
        for (int kc = 4; kc < 8; ++kc) {
            const int off = (rlow * 512 + kg * 16 + kc * 64) ^ rswz;
            const short8 ah = *(const short8*)(hbase + off);
            const short8 al = *(const short8*)(lbase + off);
            bHH[0] = __builtin_amdgcn_mfma_f32_16x16x32_bf16(ah, wh[0][kc], bHH[0], 0, 0, 0);
            bHH[1] = __builtin_amdgcn_mfma_f32_16x16x32_bf16(ah, wh[1][kc], bHH[1], 0, 0, 0);
            bHL[0] = __builtin_amdgcn_mfma_f32_16x16x32_bf16(ah, wl[0][kc], bHL[0], 0, 0, 0);
            bHL[1] = __builtin_amdgcn_mfma_f32_16x16x32_bf16(ah, wl[1][kc], bHL[1], 0, 0, 0);
            bLH[0] = __builtin_amdgcn_mfma_f32_16x16x32_bf16(al, wh[0][kc], bLH[0], 0, 0, 0);
            bLH[1] = __builtin_amdgcn_mfma_f32_16x16x32_bf16(al, wh[1][kc], bLH[1], 0, 0, 0);
        }
        __builtin_amdgcn_sched_barrier(0);
        asm volatile("s_waitcnt lgkmcnt(0)" ::: "memory");
        __builtin_amdgcn_s_barrier();
        __builtin_amdgcn_sched_barrier(0);

        if (kg == p - 1) {
            #pragma unroll
            for (int tile = 0; tile < 2; ++tile) {
                const int col = col0 + tile * 16 + rlow;
                #pragma unroll
                for (int q = 0; q < 4; ++q) {
                    const float cv = gst[((size_t)(b0 + q) * 3 + (p - 1)) * 256 + col];
                    const float yv = (aHH[tile][q] + bHH[tile][q]) + (aHL[tile][q] + bHL[tile][q])
                                   + (aLH[tile][q] + bLH[tile][q]) + cv;
                    const int wr = p * 4 + q;
                    const unsigned short hb = f2bf(yv);
                    const unsigned short lb = f2bf(yv - bf2f(hb));
                    const int byte = (wr * 512 + col * 2) ^ ((wr & 7) << 4);
                    *(unsigned short*)((char*)&cbuf[0][0][0] + byte) = hb;
                    *(unsigned short*)((char*)&cbuf[0][1][0] + byte) = lb;
                    gyp[(size_t)(b0 + q) * 65536 + (size_t)p * 256 + col] = yv;
                }
            }
        }
        __builtin_amdgcn_sched_barrier(0);
        asm volatile("s_waitcnt lgkmcnt(0)" ::: "memory");
        __builtin_amdgcn_s_barrier();
        __builtin_amdgcn_sched_barrier(0);
    }

    gather_frags(W4, col0, rlow, kg, wh, wl);

    float dv[2][4];
    #pragma unroll
    for (int tile = 0; tile < 2; ++tile) {
        const int col = col0 + tile * 16 + rlow;
        #pragma unroll
        for (int q = 0; q < 4; ++q)
            dv[tile][q] = gyp[(size_t)(b0 + q) * 65536 + (size_t)(4 + kg) * 256 + col];
    }

    int cur = 0;
    for (int s = 0; s < 63; ++s) {
        const int tb = 4 + s * 4;

        float dn[2][4];
        if (s < 62) {
            #pragma unroll
            for (int tile = 0; tile < 2; ++tile) {
                const int col = col0 + tile * 16 + rlow;
                #pragma unroll
                for (int q = 0; q < 4; ++q)
                    dn[tile][q] = gyp[(size_t)(b0 + q) * 65536
                                      + (size_t)(tb + 4 + kg) * 256 + col];
            }
        }

        f32x4 aHH[2], aHL[2], aLH[2], bHH[2], bHL[2], bLH[2];
        #pragma unroll
        for (int tile = 0; tile < 2; ++tile) {
            aHH[tile] = {0.f,0.f,0.f,0.f}; aHL[tile] = {0.f,0.f,0.f,0.f}; aLH[tile] = {0.f,0.f,0.f,0.f};
            bHH[tile] = {0.f,0.f,0.f,0.f}; bHL[tile] = {0.f,0.f,0.f,0.f}; bLH[tile] = {0.f,0.f,0.f,0.f};
        }
        const char* hbase = (const char*)&cbuf[cur][0][0];
        const char* lbase = (const char*)&cbuf[cur][1][0];
        #pragma unroll
        for (int kc = 0; kc < 4; ++kc) {
            const int off = (rlow * 512 + kg * 16 + kc * 64) ^ rswz;
            const short8 ah = *(const short8*)(hbase + off);
            const short8 al = *(const short8*)(lbase + off);
            aHH[0] = __builtin_amdgcn_mfma_f32_16x16x32_bf16(ah, wh[0][kc], aHH[0], 0, 0, 0);
            aHH[1] = __builtin_amdgcn_mfma_f32_16x16x32_bf16(ah, wh[1][kc], aHH[1], 0, 0, 0);
            aHL[0] = __builtin_amdgcn_mfma_f32_16x16x32_bf16(ah, wl[0][kc], aHL[0], 0, 0, 0);
            aHL[1] = __builtin_amdgcn_mfma_f32_16x16x32_bf16(ah, wl[1][kc], aHL[1], 0, 0, 0);
            aLH[0] = __builtin_amdgcn_mfma_f32_16x16x32_bf16(al, wh[0][kc], aLH[0], 0, 0, 0);
            aLH[1] = __builtin_amdgcn_mfma_f32_16x16x32_bf16(al, wh[1][kc], aLH[1], 0, 0, 0);
        }
        #pragma unroll
        for (int kc = 4; kc < 8; ++kc) {
            const int off = (rlow * 512 + kg * 16 + kc * 64) ^ rswz;
            const short8 ah = *(const short8*)(hbase + off);
            const short8 al = *(const short8*)(lbase + off);
            bHH[0] = __builtin_amdgcn_mfma_f32_16x16x32_bf16(ah, wh[0][kc], bHH[0], 0, 0, 0);
            bHH[1] = __builtin_amdgcn_mfma_f32_16x16x32_bf16(ah, wh[1][kc], bHH[1], 0, 0, 0);
            bHL[0] = __builtin_amdgcn_mfma_f32_16x16x32_bf16(ah, wl[0][kc], bHL[0], 0, 0, 0);
            bHL[1] = __builtin_amdgcn_mfma_f32_16x16x32_bf16(ah, wl[1][kc], bHL[1], 0, 0, 0);
            bLH[0] = __builtin_amdgcn_mfma_f32_16x16x32_bf16(al, wh[0][kc], bLH[0], 0, 0, 0);
            bLH[1] = __builtin_amdgcn_mfma_f32_16x16x32_bf16(al, wh[1][kc], bLH[1], 0, 0, 0);
        }

        char* whb = (char*)&cbuf[cur ^ 1][0][0];
        char* wlb = (char*)&cbuf[cur ^ 1][1][0];
        #pragma unroll
        for (int tile = 0; tile < 2; ++tile) {
            const int col = col0 + tile * 16 + rlow;
            #pragma unroll
            for (int q = 0; q < 4; ++q) {
                const int row = kg * 4 + q;
                const float yv = (aHH[tile][q] + bHH[tile][q]) + (aHL[tile][q] + bHL[tile][q])
                               + (aLH[tile][q] + bLH[tile][q]) + dv[tile][q];
                const unsigned short hb = f2bf(yv);
                const unsigned short lb = f2bf(yv - bf2f(hb));
                const int byte = (row * 512 + col * 2) ^ ((row & 7) << 4);
                *(unsigned short*)(whb + byte) = hb;
                *(unsigned short*)(wlb + byte) = lb;
                gyp[(size_t)(b0 + q) * 65536 + (size_t)(tb + kg) * 256 + col] = yv;
            }
        }
        if (s < 62) {
            #pragma unroll
            for (int tile = 0; tile < 2; ++tile)
                #pragma unroll
                for (int q = 0; q < 4; ++q)
                    dv[tile][q] = dn[tile][q];
        }

        __builtin_amdgcn_sched_barrier(0);
        asm volatile("s_waitcnt lgkmcnt(0)" ::: "memory");
        __builtin_amdgcn_s_barrier();
        __builtin_amdgcn_sched_barrier(0);
        cur ^= 1;
    }
}

// ---------------------------------------------------------------------------
extern "C" void kernel_launch(void* const* d_in, const int* in_sizes, int n_in,
                              void* d_out, int out_size, void* d_ws, size_t ws_size,
                              hipStream_t stream)
{
    const float* x   = (const float*)d_in[0];
    const float* u   = (const float*)d_in[1];
    const float* Wx1 = (const float*)d_in[2];
    const float* bx1 = (const float*)d_in[3];
    const float* Wx2 = (const float*)d_in[4];
    const float* bx2 = (const float*)d_in[5];
    const float* Wx3 = (const float*)d_in[6];
    const float* Wu1 = (const float*)d_in[7];
    const float* bu1 = (const float*)d_in[8];
    const float* Wu2 = (const float*)d_in[9];
    const float* WB  = (const float*)d_in[10];
    const float* WK  = (const float*)d_in[11];
    const float* bK  = (const float*)d_in[12];

    float* y  = (float*)d_out;
    float* yp = y + (size_t)MM * 256;

    char* ws = (char*)d_ws;
    __hip_bfloat16* x_bf = (__hip_bfloat16*)(ws);
    __hip_bfloat16* u_bf = (__hip_bfloat16*)(ws + 16777216);
    __hip_bfloat16* wTb  = (__hip_bfloat16*)(ws + 33554432);
    __hip_bfloat16* Wx1T = wTb;
    __hip_bfloat16* Wx2T = wTb + 16384;
    __hip_bfloat16* Wx3T = wTb + 81920;
    __hip_bfloat16* Wu1T = wTb + 131072;
    __hip_bfloat16* Wu2T = wTb + 147456;
    __hip_bfloat16* WBT  = wTb + 196608;
    __hip_bfloat16* t2   = (__hip_bfloat16*)(ws + 34078720);     // v (M x 192)
    float* W2f   = (float*)(ws + 101187584);
    float* W3f   = (float*)(ws + 101449728);
    float* W4f   = (float*)(ws + 101711872);
    float* WBWf  = (float*)(ws + 101974016);
    float* WBW2f = (float*)(ws + 102236160);
    float* WBW3f = (float*)(ws + 102498304);
    __hip_bfloat16* WBT4 = (__hip_bfloat16*)(ws + 102760448);
    float* cK4   = (float*)(ws + 103284736);
    float* stash = (float*)(ws + 103285760);

    prepA<<<17440, dim3(256), 0, stream>>>(x, u, x_bf, u_bf, y,
        Wx1, Wx2, Wx3, Wu1, Wu2, WB,
        Wx1T, Wx2T, Wx3T, Wu1T, Wu2T, WBT,
        WK, WB, W2f, WBWf);

    {
        G5 L2 = {{W2f, W2f, WBWf, WBWf, nullptr},
                 {WK, W2f, WK, W2f, nullptr},
                 {W3f, W4f, WBW2f, WBW3f, nullptr}};
        wgemm<<<64, dim3(256), 0, stream>>>(L2);
    }

    ffC<<<2561, dim3(512), 0, stream>>>(x_bf, u_bf,
        Wx1T, bx1, Wx2T, bx2, Wx3T, Wu1T, bu1, Wu2T,
        y, t2,
        WB, WBWf, WBW2f, WBW3f, WBT4,
        bK, WK, W2f, W3f, cK4);

    d4gS<<<2560, dim3(256), 0, stream>>>(u_bf, t2, WBT4, cK4, yp, WBT, bK, stash);

    scan4<<<128, dim3(512), 0, stream>>>(WK, W4f, stash, y, yp);
}